// Round 1
// baseline (7087.680 us; speedup 1.0000x reference)
//
#include <hip/hip_runtime.h>
#include <math.h>

// Problem constants (from reference setup_inputs): B=16, A=16384, C=81, TOP_K=64
constexpr int B_N  = 16;
constexpr int A_N  = 16384;
constexpr int C_N  = 81;
constexpr int TOPK = 64;
constexpr int NT   = 256;            // threads per NMS block (4 waves)
constexpr int PER  = A_N / NT;       // 64 anchors owned per thread (register-resident)

// ---------------------------------------------------------------------------
// Kernel 1: SSD box decode. boxes[b,a] = corners from loc[b,a] + anchors[a].
// One thread per (b,a); all loads/stores are coalesced float4.
// ---------------------------------------------------------------------------
__global__ __launch_bounds__(NT) void decode_kernel(const float4* __restrict__ loc,
                                                    const float4* __restrict__ anch,
                                                    float4* __restrict__ boxes) {
    int i = blockIdx.x * NT + threadIdx.x;   // i = b*A_N + a, grid sized exactly
    int a = i & (A_N - 1);
    float4 l  = loc[i];
    float4 an = anch[a];
    // cxcy = anchors[:, :2] + loc[:, :2] * 0.1 * anchors[:, 2:]
    float cx = an.x + (l.x * 0.1f) * an.z;
    float cy = an.y + (l.y * 0.1f) * an.w;
    // wh = anchors[:, 2:] * exp(loc[:, 2:] * 0.2)
    float w  = an.z * expf(l.z * 0.2f);
    float h  = an.w * expf(l.w * 0.2f);
    float x1 = cx - w * 0.5f;
    float y1 = cy - h * 0.5f;
    boxes[i] = make_float4(x1, y1, x1 + w, y1 + h);
}

// ---------------------------------------------------------------------------
// Kernel 2: per-(batch,class) greedy NMS. One block per lane.
// Scores live in registers (PER=64 per thread, fully unrolled => no LDS array,
// no dynamic indexing). Incremental per-thread argmax: scores only decrease,
// so the running best is valid until one of this thread's entries is killed.
// ---------------------------------------------------------------------------
__global__ __launch_bounds__(NT) void nms_kernel(const float* __restrict__ conf,
                                                 const float4* __restrict__ boxes,
                                                 float* __restrict__ out) {
    __shared__ float rv[NT / 64];
    __shared__ int   ri[NT / 64];
    __shared__ float s_val;
    __shared__ int   s_idx;

    const int c    = blockIdx.x;
    const int b    = blockIdx.y;
    const int tid  = threadIdx.x;
    const int lane = tid & 63;
    const int wv   = tid >> 6;

    // Load scores: sigmoid(conf[b, a, c]), threshold 0.3 -> -1 sentinel.
    float sreg[PER];
    const float* cptr = conf + (size_t)b * A_N * C_N + c;
#pragma unroll
    for (int j = 0; j < PER; ++j) {
        int a = tid + j * NT;
        float x   = cptr[(size_t)a * C_N];
        float sig = 1.0f / (1.0f + expf(-x));
        sreg[j] = (sig > 0.3f) ? sig : -1.0f;
    }

    const float4* bptr = boxes + (size_t)b * A_N;
    float* optr = out + ((size_t)(b * C_N + c)) * TOPK * 5;

    float bestv = -2.0f;
    int   besti = 0x7fffffff;
    bool  dirty = true;

    int k = 0;
    for (; k < TOPK; ++k) {
        // --- per-thread argmax (rescan only if an owned entry was killed) ---
        if (dirty) {
            bestv = -2.0f; besti = 0x7fffffff;
#pragma unroll
            for (int j = 0; j < PER; ++j) {
                int a = tid + j * NT;
                float v = sreg[j];
                if (v > bestv) { bestv = v; besti = a; }  // ascending a => first-index on ties
            }
            dirty = false;
        }
        // --- wave reduce (max score, then min index on ties = jnp.argmax) ---
        float bv = bestv; int bi = besti;
#pragma unroll
        for (int off = 32; off > 0; off >>= 1) {
            float ov = __shfl_down(bv, off, 64);
            int   oi = __shfl_down(bi, off, 64);
            if (ov > bv || (ov == bv && oi < bi)) { bv = ov; bi = oi; }
        }
        if (lane == 0) { rv[wv] = bv; ri[wv] = bi; }
        __syncthreads();
        if (tid == 0) {
            float v = rv[0]; int i0 = ri[0];
#pragma unroll
            for (int w = 1; w < NT / 64; ++w) {
                if (rv[w] > v || (rv[w] == v && ri[w] < i0)) { v = rv[w]; i0 = ri[w]; }
            }
            s_val = v; s_idx = i0;
        }
        __syncthreads();
        const float sel  = s_val;
        const int   sidx = s_idx;

        if (sel <= 0.0f) break;   // keep==false => all remaining rows are zeros

        float4 sb = bptr[sidx];   // same address across lanes -> broadcast load
        if (tid == 0) {
            float* o = optr + (size_t)k * 5;
            o[0] = sel; o[1] = sb.x; o[2] = sb.y; o[3] = sb.z; o[4] = sb.w;
        }
        const float sax = (sb.z - sb.x) * (sb.w - sb.y);

        // --- suppression: IoU(selected, a) > 0.5 -> kill. Owner thread also
        //     kills the selected index itself (covers NaN self-IoU edge). ---
#pragma unroll
        for (int j = 0; j < PER; ++j) {
            int a = tid + j * NT;
            if (a == sidx) {
                sreg[j] = -1.0f;
                if (besti == a) dirty = true;
            } else if (sreg[j] > 0.0f) {
                float4 bb = bptr[a];          // coalesced float4 (stride NT over a)
                float tlx = fmaxf(sb.x, bb.x);
                float tly = fmaxf(sb.y, bb.y);
                float brx = fminf(sb.z, bb.z);
                float bry = fminf(sb.w, bb.w);
                float iw  = fmaxf(brx - tlx, 0.0f);
                float ih  = fmaxf(bry - tly, 0.0f);
                float inter = iw * ih;
                float a2  = (bb.z - bb.x) * (bb.w - bb.y);
                float iou = inter / (sax + a2 - inter);
                if (iou > 0.5f) {
                    sreg[j] = -1.0f;
                    if (besti == a) dirty = true;
                }
            }
        }
        // no barrier needed: suppression touches only per-thread registers;
        // rv/ri rewrites next iteration are ordered by this iteration's barriers
    }

    // Zero-fill remaining rows (harness poisons d_out with 0xAA every launch).
    {
        float* o  = optr + (size_t)k * 5;
        int   rem = (TOPK - k) * 5;
        for (int t = tid; t < rem; t += NT) o[t] = 0.0f;
    }
}

extern "C" void kernel_launch(void* const* d_in, const int* in_sizes, int n_in,
                              void* d_out, int out_size, void* d_ws, size_t ws_size,
                              hipStream_t stream) {
    const float* loc     = (const float*)d_in[0];   // [B, A, 4]
    const float* conf    = (const float*)d_in[1];   // [B, A, C]
    const float* anchors = (const float*)d_in[2];   // [A, 4]
    float* out = (float*)d_out;                     // [B, C, TOPK, 5]

    float4* boxes = (float4*)d_ws;                  // B*A float4 = 4 MB scratch

    decode_kernel<<<(B_N * A_N) / NT, NT, 0, stream>>>(
        (const float4*)loc, (const float4*)anchors, boxes);

    nms_kernel<<<dim3(C_N, B_N), NT, 0, stream>>>(conf, boxes, out);
}

// Round 2
// 2116.459 us; speedup vs baseline: 3.3488x; 3.3488x over previous
//
#include <hip/hip_runtime.h>
#include <math.h>

// Problem constants (from reference setup_inputs): B=16, A=16384, C=81, TOP_K=64
constexpr int B_N  = 16;
constexpr int A_N  = 16384;
constexpr int C_N  = 81;
constexpr int TOPK = 64;
constexpr int DNT  = 256;            // decode kernel block size
constexpr int NT   = 1024;           // NMS block size (16 waves)
constexpr int PER  = A_N / NT;       // 16 anchors owned per thread (all register-resident)
constexpr int NW   = NT / 64;        // 16 waves per block

// ---------------------------------------------------------------------------
// Kernel 1: SSD box decode (unchanged from round 1 — arithmetic proven).
// ---------------------------------------------------------------------------
__global__ __launch_bounds__(DNT) void decode_kernel(const float4* __restrict__ loc,
                                                     const float4* __restrict__ anch,
                                                     float4* __restrict__ boxes) {
    int i = blockIdx.x * DNT + threadIdx.x;
    int a = i & (A_N - 1);
    float4 l  = loc[i];
    float4 an = anch[a];
    float cx = an.x + (l.x * 0.1f) * an.z;
    float cy = an.y + (l.y * 0.1f) * an.w;
    float w  = an.z * expf(l.z * 0.2f);
    float h  = an.w * expf(l.w * 0.2f);
    float x1 = cx - w * 0.5f;
    float y1 = cy - h * 0.5f;
    boxes[i] = make_float4(x1, y1, x1 + w, y1 + h);
}

// ---------------------------------------------------------------------------
// Kernel 2: per-(batch,class) greedy NMS. One 1024-thread block per lane.
// Scores AND boxes are register-resident (PER=16 per thread => 80 array VGPRs),
// so the suppression loop is pure branchless VALU with no memory traffic.
// Arithmetic (sigmoid via expf, IEEE-div IoU) is bit-identical to the round-1
// kernel that passed validation — only the tiling changed.
// ---------------------------------------------------------------------------
__global__ __launch_bounds__(NT) void nms_kernel(const float* __restrict__ conf,
                                                 const float4* __restrict__ boxes,
                                                 float* __restrict__ out) {
    __shared__ float rv[NW];
    __shared__ int   ri[NW];
    __shared__ float s_val;
    __shared__ int   s_idx;

    const int c    = blockIdx.x;
    const int b    = blockIdx.y;
    const int tid  = threadIdx.x;
    const int lane = tid & 63;
    const int wv   = tid >> 6;

    float sreg[PER];
    float bx1[PER], by1[PER], bx2[PER], by2[PER];

    const float*  cptr = conf  + (size_t)b * A_N * C_N + c;
    const float4* bptr = boxes + (size_t)b * A_N;

#pragma unroll
    for (int j = 0; j < PER; ++j) {
        int a = tid + j * NT;                    // thread's entries ascend in a
        float x   = cptr[(size_t)a * C_N];
        float sig = 1.0f / (1.0f + expf(-x));
        sreg[j] = (sig > 0.3f) ? sig : -1.0f;
        float4 bb = bptr[a];                     // coalesced float4
        bx1[j] = bb.x; by1[j] = bb.y; bx2[j] = bb.z; by2[j] = bb.w;
    }

    float* optr = out + ((size_t)(b * C_N + c)) * TOPK * 5;

    int k = 0;
    for (; k < TOPK; ++k) {
        // --- per-thread argmax over 16 register entries (always rescan) ---
        float bv = -2.0f;
        int   bi = 0x7fffffff;
#pragma unroll
        for (int j = 0; j < PER; ++j) {
            float v = sreg[j];
            int   a = tid + j * NT;
            if (v > bv) { bv = v; bi = a; }      // strict > + ascending a => first-index ties
        }
        // --- wave reduce: max score, min index on ties (jnp.argmax semantics) ---
#pragma unroll
        for (int off = 32; off > 0; off >>= 1) {
            float ov = __shfl_down(bv, off, 64);
            int   oi = __shfl_down(bi, off, 64);
            if (ov > bv || (ov == bv && oi < bi)) { bv = ov; bi = oi; }
        }
        if (lane == 0) { rv[wv] = bv; ri[wv] = bi; }
        __syncthreads();
        // --- cross-wave reduce on wave 0 (16 partials) ---
        if (wv == 0) {
            float v  = (lane < NW) ? rv[lane] : -3.0f;
            int   i0 = (lane < NW) ? ri[lane] : 0x7fffffff;
#pragma unroll
            for (int off = 8; off > 0; off >>= 1) {
                float ov = __shfl_down(v, off, 64);
                int   oi = __shfl_down(i0, off, 64);
                if (ov > v || (ov == v && oi < i0)) { v = ov; i0 = oi; }
            }
            if (lane == 0) { s_val = v; s_idx = i0; }
        }
        __syncthreads();
        const float sel  = s_val;
        const int   sidx = s_idx;

        if (sel <= 0.0f) break;   // keep==false => all remaining rows zero

        float4 sb = bptr[sidx];   // uniform address -> broadcast load (L1/L2 hit)
        if (tid == 0) {
            float* o = optr + (size_t)k * 5;
            o[0] = sel; o[1] = sb.x; o[2] = sb.y; o[3] = sb.z; o[4] = sb.w;
        }
        const float sax = (sb.z - sb.x) * (sb.w - sb.y);
        const int   rel = sidx - tid;            // selected index relative to this thread

        // --- branchless suppression, registers only ---
#pragma unroll
        for (int j = 0; j < PER; ++j) {
            float tlx = fmaxf(sb.x, bx1[j]);
            float tly = fmaxf(sb.y, by1[j]);
            float brx = fminf(sb.z, bx2[j]);
            float bry = fminf(sb.w, by2[j]);
            float iw  = fmaxf(brx - tlx, 0.0f);
            float ih  = fmaxf(bry - tly, 0.0f);
            float inter = iw * ih;
            float a2  = (bx2[j] - bx1[j]) * (by2[j] - by1[j]);
            float iou = inter / (sax + a2 - inter);    // IEEE div, matches reference
            bool self = (rel == j * NT);               // covers NaN self-IoU edge
            bool kill = self || (sreg[j] > 0.0f && iou > 0.5f);
            sreg[j] = kill ? -1.0f : sreg[j];
        }
        // no barrier needed: suppression touches only private registers; the
        // next iteration's rv/ri writes are ordered by this iteration's barriers
    }

    // Zero-fill remaining rows (harness poisons d_out with 0xAA every launch).
    {
        float* o  = optr + (size_t)k * 5;
        int   rem = (TOPK - k) * 5;
        for (int t = tid; t < rem; t += NT) o[t] = 0.0f;
    }
}

extern "C" void kernel_launch(void* const* d_in, const int* in_sizes, int n_in,
                              void* d_out, int out_size, void* d_ws, size_t ws_size,
                              hipStream_t stream) {
    const float* loc     = (const float*)d_in[0];   // [B, A, 4]
    const float* conf    = (const float*)d_in[1];   // [B, A, C]
    const float* anchors = (const float*)d_in[2];   // [A, 4]
    float* out = (float*)d_out;                     // [B, C, TOPK, 5]

    float4* boxes = (float4*)d_ws;                  // B*A float4 = 4 MB scratch

    decode_kernel<<<(B_N * A_N) / DNT, DNT, 0, stream>>>(
        (const float4*)loc, (const float4*)anchors, boxes);

    nms_kernel<<<dim3(C_N, B_N), NT, 0, stream>>>(conf, boxes, out);
}

// Round 3
// 1980.297 us; speedup vs baseline: 3.5791x; 1.0688x over previous
//
#include <hip/hip_runtime.h>
#include <math.h>

// Problem constants (from reference setup_inputs): B=16, A=16384, C=81, TOP_K=64
constexpr int B_N  = 16;
constexpr int A_N  = 16384;
constexpr int C_N  = 81;
constexpr int TOPK = 64;
constexpr int DNT  = 256;            // decode kernel block size
constexpr int NT   = 1024;           // NMS block size (16 waves)
constexpr int PER  = A_N / NT;       // 16 anchors owned per thread
constexpr int NW   = NT / 64;        // 16 waves per block

// ---------------------------------------------------------------------------
// Kernel 1: SSD box decode (unchanged — arithmetic proven bit-exact vs ref).
// ---------------------------------------------------------------------------
__global__ __launch_bounds__(DNT) void decode_kernel(const float4* __restrict__ loc,
                                                     const float4* __restrict__ anch,
                                                     float4* __restrict__ boxes) {
    int i = blockIdx.x * DNT + threadIdx.x;
    int a = i & (A_N - 1);
    float4 l  = loc[i];
    float4 an = anch[a];
    float cx = an.x + (l.x * 0.1f) * an.z;
    float cy = an.y + (l.y * 0.1f) * an.w;
    float w  = an.z * expf(l.z * 0.2f);
    float h  = an.w * expf(l.w * 0.2f);
    float x1 = cx - w * 0.5f;
    float y1 = cy - h * 0.5f;
    boxes[i] = make_float4(x1, y1, x1 + w, y1 + h);
}

// ---------------------------------------------------------------------------
// Kernel 2: per-(batch,class) greedy NMS. One 1024-thread block per lane.
// __launch_bounds__(NT, 4): 4 waves/EU min => VGPR cap 128, so the 80 array
// VGPRs (sreg[16] + 4x box[16]) stay IN REGISTERS (round 2 spilled at the
// compiler's 64-VGPR choice: WRITE_SIZE 77 MB of scratch traffic).
// Arithmetic (sigmoid via expf, IEEE-div IoU) unchanged from passing rounds.
// ---------------------------------------------------------------------------
__global__ __launch_bounds__(NT, 4) void nms_kernel(const float* __restrict__ conf,
                                                    const float4* __restrict__ boxes,
                                                    float* __restrict__ out) {
    __shared__ float rv[NW];
    __shared__ int   ri[NW];
    __shared__ float s_val;
    __shared__ int   s_idx;

    const int c    = blockIdx.x;
    const int b    = blockIdx.y;
    const int tid  = threadIdx.x;
    const int lane = tid & 63;
    const int wv   = tid >> 6;

    float sreg[PER];
    float bx1[PER], by1[PER], bx2[PER], by2[PER];

    const float*  cptr = conf  + (size_t)b * A_N * C_N + c;
    const float4* bptr = boxes + (size_t)b * A_N;

#pragma unroll
    for (int j = 0; j < PER; ++j) {
        int a = tid + j * NT;                    // thread's entries ascend in a
        float x   = cptr[(size_t)a * C_N];
        float sig = 1.0f / (1.0f + expf(-x));
        sreg[j] = (sig > 0.3f) ? sig : -1.0f;
        float4 bb = bptr[a];                     // coalesced float4
        bx1[j] = bb.x; by1[j] = bb.y; bx2[j] = bb.z; by2[j] = bb.w;
    }

    float* optr = out + ((size_t)(b * C_N + c)) * TOPK * 5;

    int k = 0;
    for (; k < TOPK; ++k) {
        // --- per-thread argmax over 16 register entries ---
        float bv = -2.0f;
        int   bi = 0x7fffffff;
#pragma unroll
        for (int j = 0; j < PER; ++j) {
            float v = sreg[j];
            int   a = tid + j * NT;
            if (v > bv) { bv = v; bi = a; }      // strict > + ascending a => first-index ties
        }
        // --- wave reduce: max score, min index on ties (jnp.argmax semantics) ---
#pragma unroll
        for (int off = 32; off > 0; off >>= 1) {
            float ov = __shfl_down(bv, off, 64);
            int   oi = __shfl_down(bi, off, 64);
            if (ov > bv || (ov == bv && oi < bi)) { bv = ov; bi = oi; }
        }
        if (lane == 0) { rv[wv] = bv; ri[wv] = bi; }
        __syncthreads();
        // --- cross-wave reduce on wave 0 (16 partials) ---
        if (wv == 0) {
            float v  = (lane < NW) ? rv[lane] : -3.0f;
            int   i0 = (lane < NW) ? ri[lane] : 0x7fffffff;
#pragma unroll
            for (int off = 8; off > 0; off >>= 1) {
                float ov = __shfl_down(v, off, 64);
                int   oi = __shfl_down(i0, off, 64);
                if (ov > v || (ov == v && oi < i0)) { v = ov; i0 = oi; }
            }
            if (lane == 0) { s_val = v; s_idx = i0; }
        }
        __syncthreads();
        const float sel  = s_val;
        const int   sidx = s_idx;

        if (sel <= 0.0f) break;   // keep==false => all remaining rows zero

        float4 sb = bptr[sidx];   // uniform address -> broadcast load (L2 hit)
        if (tid == 0) {
            float* o = optr + (size_t)k * 5;
            o[0] = sel; o[1] = sb.x; o[2] = sb.y; o[3] = sb.z; o[4] = sb.w;
        }
        const float sax = (sb.z - sb.x) * (sb.w - sb.y);
        const int   rel = sidx - tid;            // selected index relative to this thread

        // --- branchless suppression, registers only. Note: re-killing an
        //     already-dead entry is a no-op (matches ref's jnp.where), so no
        //     sreg>0 guard is needed. Self-kill covers the NaN self-IoU edge. ---
#pragma unroll
        for (int j = 0; j < PER; ++j) {
            float tlx = fmaxf(sb.x, bx1[j]);
            float tly = fmaxf(sb.y, by1[j]);
            float brx = fminf(sb.z, bx2[j]);
            float bry = fminf(sb.w, by2[j]);
            float iw  = fmaxf(brx - tlx, 0.0f);
            float ih  = fmaxf(bry - tly, 0.0f);
            float inter = iw * ih;
            float a2  = (bx2[j] - bx1[j]) * (by2[j] - by1[j]);
            float iou = inter / (sax + a2 - inter);    // IEEE div, matches reference
            bool kill = (rel == j * NT) || (iou > 0.5f);
            sreg[j] = kill ? -1.0f : sreg[j];
        }
        // no barrier needed: suppression touches only private registers; the
        // next iteration's rv/ri writes are ordered by this iteration's barriers
    }

    // Zero-fill remaining rows (harness poisons d_out with 0xAA every launch).
    {
        float* o  = optr + (size_t)k * 5;
        int   rem = (TOPK - k) * 5;
        for (int t = tid; t < rem; t += NT) o[t] = 0.0f;
    }
}

extern "C" void kernel_launch(void* const* d_in, const int* in_sizes, int n_in,
                              void* d_out, int out_size, void* d_ws, size_t ws_size,
                              hipStream_t stream) {
    const float* loc     = (const float*)d_in[0];   // [B, A, 4]
    const float* conf    = (const float*)d_in[1];   // [B, A, C]
    const float* anchors = (const float*)d_in[2];   // [A, 4]
    float* out = (float*)d_out;                     // [B, C, TOPK, 5]

    float4* boxes = (float4*)d_ws;                  // B*A float4 = 4 MB scratch

    decode_kernel<<<(B_N * A_N) / DNT, DNT, 0, stream>>>(
        (const float4*)loc, (const float4*)anchors, boxes);

    nms_kernel<<<dim3(C_N, B_N), NT, 0, stream>>>(conf, boxes, out);
}

// Round 4
// 474.635 us; speedup vs baseline: 14.9329x; 4.1723x over previous
//
#include <hip/hip_runtime.h>
#include <math.h>

// Problem constants (from reference setup_inputs): B=16, A=16384, C=81, TOP_K=64
constexpr int B_N  = 16;
constexpr int A_N  = 16384;
constexpr int C_N  = 81;
constexpr int TOPK = 64;
constexpr int DNT  = 256;            // decode kernel block size
constexpr int NT   = 1024;           // NMS block size (16 waves)
constexpr int PER  = A_N / NT;       // 16 scores owned per thread
constexpr int NBINS = 232;           // score-bit bins covering (0.3, 1.0)
constexpr int CAP   = 512;           // candidate band capacity (pow2 for bitonic)
constexpr unsigned BIN_BASE = 0x3E99u;   // __float_as_uint(0.3f) >> 16

// ---------------------------------------------------------------------------
// Kernel 1: SSD box decode (unchanged — bit-exact vs ref across rounds 1-3).
// ---------------------------------------------------------------------------
__global__ __launch_bounds__(DNT) void decode_kernel(const float4* __restrict__ loc,
                                                     const float4* __restrict__ anch,
                                                     float4* __restrict__ boxes) {
    int i = blockIdx.x * DNT + threadIdx.x;
    int a = i & (A_N - 1);
    float4 l  = loc[i];
    float4 an = anch[a];
    float cx = an.x + (l.x * 0.1f) * an.z;
    float cy = an.y + (l.y * 0.1f) * an.w;
    float w  = an.z * expf(l.z * 0.2f);
    float h  = an.w * expf(l.w * 0.2f);
    float x1 = cx - w * 0.5f;
    float y1 = cy - h * 0.5f;
    boxes[i] = make_float4(x1, y1, x1 + w, y1 + h);
}

// ---------------------------------------------------------------------------
// Kernel 2: sorted-scan greedy NMS, one block per (b,c).
// Equivalence to the reference's argmax+suppress scan: suppression only masks
// scores, so the k-th argmax is the first candidate in (score desc, idx asc)
// order not IoU-suppressed (>0.5) by an earlier-accepted box. IoU formula is
// symmetric and evaluated bit-identically on the same pairs, in the same
// (accepted_area + candidate_area) operand order as the reference.
// Band-walk + refill guarantees full coverage at any suppression density.
// ---------------------------------------------------------------------------
__global__ __launch_bounds__(NT) void nms_kernel(const float* __restrict__ conf,
                                                 const float4* __restrict__ boxes,
                                                 float* __restrict__ out) {
    __shared__ int hist[NBINS];
    __shared__ unsigned long long cand[CAP];
    __shared__ int s_cnt, s_binlo, s_acc, s_kout, s_done;

    const int c    = blockIdx.x;
    const int b    = blockIdx.y;
    const int tid  = threadIdx.x;
    const int lane = tid & 63;
    const int wv   = tid >> 6;

    for (int i = tid; i < NBINS; i += NT) hist[i] = 0;
    if (tid == 0) { s_acc = 0; s_kout = 0; s_done = 0; }
    __syncthreads();

    const float*  cptr = conf  + (size_t)b * A_N * C_N + c;
    const float4* bptr = boxes + (size_t)b * A_N;
    float* optr = out + ((size_t)(b * C_N + c)) * TOPK * 5;

    // --- Phase A: sigmoid + threshold (identical math to passing rounds),
    //     histogram of score bits. Scores stay in registers for compaction. ---
    float sreg[PER];
#pragma unroll
    for (int j = 0; j < PER; ++j) {
        int a = tid + j * NT;
        float x   = cptr[(size_t)a * C_N];
        float sig = 1.0f / (1.0f + expf(-x));
        if (sig > 0.3f) {
            sreg[j] = sig;
            unsigned u = __float_as_uint(sig);
            int bin = (int)(u >> 16) - (int)BIN_BASE;
            bin = bin < 0 ? 0 : (bin > NBINS - 1 ? NBINS - 1 : bin);
            atomicAdd(&hist[bin], 1);
        } else {
            sreg[j] = -1.0f;
        }
    }
    __syncthreads();

    // Accepted boxes: one per lane of wave 0, in registers.
    float rx1 = 0.f, ry1 = 0.f, rx2 = 0.f, ry2 = 0.f, rar = 0.f;

    int bin_hi = NBINS;
    for (;;) {
        // --- band selection: top-down bins totaling <= CAP ---
        if (tid == 0) {
            int lo = bin_hi, tot = 0;
            while (lo > 0) {
                int cnt = hist[lo - 1];
                if (tot + cnt > CAP) {
                    if (tot == 0) { lo--; }   // single bin > CAP: take it (clamped)
                    break;
                }
                tot += cnt; lo--;
            }
            s_binlo = lo; s_cnt = 0;
        }
        __syncthreads();
        const int bin_lo = s_binlo;
        if (bin_lo == bin_hi) break;       // all bins consumed -> exhausted

        // --- compact this band's candidates from registers into LDS ---
#pragma unroll
        for (int j = 0; j < PER; ++j) {
            float v = sreg[j];
            if (v > 0.0f) {
                unsigned u = __float_as_uint(v);
                int bin = (int)(u >> 16) - (int)BIN_BASE;
                bin = bin < 0 ? 0 : (bin > NBINS - 1 ? NBINS - 1 : bin);
                if (bin >= bin_lo && bin < bin_hi) {
                    int slot = atomicAdd(&s_cnt, 1);
                    if (slot < CAP) {
                        unsigned a = (unsigned)(tid + j * NT);
                        // key: score desc primary, idx asc on ties (~a)
                        cand[slot] = ((unsigned long long)u << 32) | (unsigned)(~a);
                    }
                }
            }
        }
        __syncthreads();
        int C = s_cnt; if (C > CAP) C = CAP;

        if (C > 0) {
            for (int i = tid; i < CAP; i += NT) if (i >= C) cand[i] = 0ull;
            __syncthreads();
            // --- bitonic sort, descending, n = CAP ---
            for (int k = 2; k <= CAP; k <<= 1) {
                for (int j2 = k >> 1; j2 > 0; j2 >>= 1) {
                    if (tid < CAP) {
                        int p = tid ^ j2;
                        if (p > tid) {
                            unsigned long long va = cand[tid], vb = cand[p];
                            bool up = ((tid & k) == 0);
                            bool sw = up ? (va < vb) : (va > vb);
                            if (sw) { cand[tid] = vb; cand[p] = va; }
                        }
                    }
                    __syncthreads();
                }
            }

            // --- Phase B: ordered greedy scan on wave 0 ---
            if (wv == 0) {
                int acc  = s_acc;
                int kout = s_kout;
                int t = 0;
                unsigned long long key = cand[0];
                float4 cb = bptr[(int)(~(unsigned)key)];
                while (t < C) {
                    // prefetch next candidate's box (hide L2 latency)
                    unsigned long long nkey = 0ull;
                    float4 nb = cb;
                    if (t + 1 < C) {
                        nkey = cand[t + 1];
                        nb = bptr[(int)(~(unsigned)nkey)];
                    }
                    float sc = __uint_as_float((unsigned)(key >> 32));
                    float ca = (cb.z - cb.x) * (cb.w - cb.y);
                    bool over = false;
                    if (lane < acc) {
                        float tlx = fmaxf(rx1, cb.x);
                        float tly = fmaxf(ry1, cb.y);
                        float brx = fminf(rx2, cb.z);
                        float bry = fminf(ry2, cb.w);
                        float iw  = fmaxf(brx - tlx, 0.0f);
                        float ih  = fmaxf(bry - tly, 0.0f);
                        float inter = iw * ih;
                        float iou = inter / (rar + ca - inter);  // (a1=accepted)+(a2=cand), ref order
                        over = iou > 0.5f;
                    }
                    if (!__any(over)) {
                        if (lane == acc) { rx1 = cb.x; ry1 = cb.y; rx2 = cb.z; ry2 = cb.w; rar = ca; }
                        if (lane == 0) {
                            float* o = optr + (size_t)kout * 5;
                            o[0] = sc; o[1] = cb.x; o[2] = cb.y; o[3] = cb.z; o[4] = cb.w;
                        }
                        acc++; kout++;
                        if (acc == TOPK) break;
                    }
                    ++t; key = nkey; cb = nb;
                }
                if (lane == 0) { s_acc = acc; s_kout = kout; s_done = (acc == TOPK) ? 1 : 0; }
            }
            __syncthreads();
            if (s_done) break;
        }
        bin_hi = bin_lo;
    }

    __syncthreads();
    const int kout = s_kout;
    // Zero-fill remaining rows (harness poisons d_out with 0xAA every launch).
    {
        float* o  = optr + (size_t)kout * 5;
        int   rem = (TOPK - kout) * 5;
        for (int t = tid; t < rem; t += NT) o[t] = 0.0f;
    }
}

extern "C" void kernel_launch(void* const* d_in, const int* in_sizes, int n_in,
                              void* d_out, int out_size, void* d_ws, size_t ws_size,
                              hipStream_t stream) {
    const float* loc     = (const float*)d_in[0];   // [B, A, 4]
    const float* conf    = (const float*)d_in[1];   // [B, A, C]
    const float* anchors = (const float*)d_in[2];   // [A, 4]
    float* out = (float*)d_out;                     // [B, C, TOPK, 5]

    float4* boxes = (float4*)d_ws;                  // B*A float4 = 4 MB scratch

    decode_kernel<<<(B_N * A_N) / DNT, DNT, 0, stream>>>(
        (const float4*)loc, (const float4*)anchors, boxes);

    nms_kernel<<<dim3(C_N, B_N), NT, 0, stream>>>(conf, boxes, out);
}

// Round 5
// 380.728 us; speedup vs baseline: 18.6161x; 1.2467x over previous
//
#include <hip/hip_runtime.h>
#include <math.h>

// Problem constants (from reference setup_inputs): B=16, A=16384, C=81, TOP_K=64
constexpr int B_N  = 16;
constexpr int A_N  = 16384;
constexpr int C_N  = 81;
constexpr int TOPK = 64;
constexpr int DNT  = 256;            // decode kernel block size
constexpr int NT   = 1024;           // NMS block size (16 waves)
constexpr int PER  = A_N / NT;       // 16 scores owned per thread
constexpr int NBINS = 232;           // score-bit bins covering (0.3, 1.0)
constexpr int CAP   = 512;           // candidate band capacity (pow2 for bitonic)
constexpr unsigned BIN_BASE = 0x3E99u;   // __float_as_uint(0.3f) >> 16

// transpose tile: 64 anchors x 81 classes per block
constexpr int TA   = 64;
constexpr int TNT  = 256;
constexpr int TILE_ELEMS = TA * C_N;     // 5184

// ---------------------------------------------------------------------------
// Kernel 1: SSD box decode (unchanged — bit-exact vs ref across rounds 1-4).
// ---------------------------------------------------------------------------
__global__ __launch_bounds__(DNT) void decode_kernel(const float4* __restrict__ loc,
                                                     const float4* __restrict__ anch,
                                                     float4* __restrict__ boxes) {
    int i = blockIdx.x * DNT + threadIdx.x;
    int a = i & (A_N - 1);
    float4 l  = loc[i];
    float4 an = anch[a];
    float cx = an.x + (l.x * 0.1f) * an.z;
    float cy = an.y + (l.y * 0.1f) * an.w;
    float w  = an.z * expf(l.z * 0.2f);
    float h  = an.w * expf(l.w * 0.2f);
    float x1 = cx - w * 0.5f;
    float y1 = cy - h * 0.5f;
    boxes[i] = make_float4(x1, y1, x1 + w, y1 + h);
}

// ---------------------------------------------------------------------------
// Kernel 1b: fused sigmoid + transpose. conf[b, a, c] -> scores_T[b, c, a].
// Each block: one batch, 64 consecutive anchors = contiguous 20.7 KB read.
// Sigmoid computed with the exact expression validated in rounds 1-4; the
// fp32 value round-trips through memory bit-exactly.
// ---------------------------------------------------------------------------
__global__ __launch_bounds__(TNT) void sigT_kernel(const float* __restrict__ conf,
                                                   float* __restrict__ scoresT) {
    __shared__ float tile[C_N][TA + 1];   // +1 pad: conflict-free both phases

    const int a0 = blockIdx.x * TA;
    const int b  = blockIdx.y;
    const int t  = threadIdx.x;

    const float* src = conf + ((size_t)b * A_N + a0) * C_N;
#pragma unroll
    for (int i = 0; i < (TILE_ELEMS + TNT - 1) / TNT; ++i) {
        int idx = i * TNT + t;
        if (idx < TILE_ELEMS) {
            float x = src[idx];                    // fully coalesced
            int al = idx / C_N;
            int cc = idx - al * C_N;
            tile[cc][al] = 1.0f / (1.0f + expf(-x));
        }
    }
    __syncthreads();
    float* dst = scoresT + (size_t)b * C_N * A_N + a0;
#pragma unroll
    for (int i = 0; i < (TILE_ELEMS + TNT - 1) / TNT; ++i) {
        int idx = i * TNT + t;
        if (idx < TILE_ELEMS) {
            int cc = idx >> 6;                     // idx / 64
            int al = idx & (TA - 1);
            dst[(size_t)cc * A_N + al] = tile[cc][al];  // 256B segments per class
        }
    }
}

// ---------------------------------------------------------------------------
// Kernel 2: sorted-scan greedy NMS, one block per (b,c). Identical selection/
// suppression semantics to the round-4 kernel that passed; only the score
// source changes (TRANSPOSED: coalesced scores_T, else strided conf+sigmoid).
// ---------------------------------------------------------------------------
template <bool TRANSPOSED>
__global__ __launch_bounds__(NT) void nms_kernel(const float* __restrict__ conf,
                                                 const float* __restrict__ scoresT,
                                                 const float4* __restrict__ boxes,
                                                 float* __restrict__ out) {
    __shared__ int hist[NBINS];
    __shared__ unsigned long long cand[CAP];
    __shared__ int s_cnt, s_binlo, s_acc, s_kout, s_done;

    const int c    = blockIdx.x;
    const int b    = blockIdx.y;
    const int tid  = threadIdx.x;
    const int lane = tid & 63;
    const int wv   = tid >> 6;

    for (int i = tid; i < NBINS; i += NT) hist[i] = 0;
    if (tid == 0) { s_acc = 0; s_kout = 0; s_done = 0; }
    __syncthreads();

    const float4* bptr = boxes + (size_t)b * A_N;
    float* optr = out + ((size_t)(b * C_N + c)) * TOPK * 5;

    // --- Phase A: scores into registers + histogram of score bits ---
    float sreg[PER];
    int   areg[PER];
    if (TRANSPOSED) {
        const float4* sptr = (const float4*)(scoresT + ((size_t)b * C_N + c) * A_N);
#pragma unroll
        for (int j4 = 0; j4 < PER / 4; ++j4) {
            int v = tid + j4 * NT;                 // float4 index, coalesced
            float4 s4 = sptr[v];
            int ab = v * 4;
            sreg[j4 * 4 + 0] = s4.x; areg[j4 * 4 + 0] = ab + 0;
            sreg[j4 * 4 + 1] = s4.y; areg[j4 * 4 + 1] = ab + 1;
            sreg[j4 * 4 + 2] = s4.z; areg[j4 * 4 + 2] = ab + 2;
            sreg[j4 * 4 + 3] = s4.w; areg[j4 * 4 + 3] = ab + 3;
        }
    } else {
        const float* cptr = conf + (size_t)b * A_N * C_N + c;
#pragma unroll
        for (int j = 0; j < PER; ++j) {
            int a = tid + j * NT;
            float x = cptr[(size_t)a * C_N];
            sreg[j] = 1.0f / (1.0f + expf(-x));
            areg[j] = a;
        }
    }
#pragma unroll
    for (int j = 0; j < PER; ++j) {
        if (sreg[j] > 0.3f) {
            unsigned u = __float_as_uint(sreg[j]);
            int bin = (int)(u >> 16) - (int)BIN_BASE;
            bin = bin < 0 ? 0 : (bin > NBINS - 1 ? NBINS - 1 : bin);
            atomicAdd(&hist[bin], 1);
        } else {
            sreg[j] = -1.0f;
        }
    }
    __syncthreads();

    // Accepted boxes: one per lane of wave 0, in registers.
    float rx1 = 0.f, ry1 = 0.f, rx2 = 0.f, ry2 = 0.f, rar = 0.f;

    int bin_hi = NBINS;
    for (;;) {
        // --- band selection: top-down bins totaling <= CAP ---
        if (tid == 0) {
            int lo = bin_hi, tot = 0;
            while (lo > 0) {
                int cnt = hist[lo - 1];
                if (tot + cnt > CAP) {
                    if (tot == 0) { lo--; }   // single bin > CAP: take it (clamped)
                    break;
                }
                tot += cnt; lo--;
            }
            s_binlo = lo; s_cnt = 0;
        }
        __syncthreads();
        const int bin_lo = s_binlo;
        if (bin_lo == bin_hi) break;       // all bins consumed -> exhausted

        // --- compact this band's candidates from registers into LDS ---
#pragma unroll
        for (int j = 0; j < PER; ++j) {
            float v = sreg[j];
            if (v > 0.0f) {
                unsigned u = __float_as_uint(v);
                int bin = (int)(u >> 16) - (int)BIN_BASE;
                bin = bin < 0 ? 0 : (bin > NBINS - 1 ? NBINS - 1 : bin);
                if (bin >= bin_lo && bin < bin_hi) {
                    int slot = atomicAdd(&s_cnt, 1);
                    if (slot < CAP) {
                        // key: score desc primary, idx asc on ties (~a)
                        cand[slot] = ((unsigned long long)u << 32) |
                                     (unsigned)(~(unsigned)areg[j]);
                    }
                }
            }
        }
        __syncthreads();
        int C = s_cnt; if (C > CAP) C = CAP;

        if (C > 0) {
            for (int i = tid; i < CAP; i += NT) if (i >= C) cand[i] = 0ull;
            __syncthreads();
            // --- bitonic sort, descending, n = CAP ---
            for (int k = 2; k <= CAP; k <<= 1) {
                for (int j2 = k >> 1; j2 > 0; j2 >>= 1) {
                    if (tid < CAP) {
                        int p = tid ^ j2;
                        if (p > tid) {
                            unsigned long long va = cand[tid], vb = cand[p];
                            bool up = ((tid & k) == 0);
                            bool sw = up ? (va < vb) : (va > vb);
                            if (sw) { cand[tid] = vb; cand[p] = va; }
                        }
                    }
                    __syncthreads();
                }
            }

            // --- Phase B: ordered greedy scan on wave 0 ---
            if (wv == 0) {
                int acc  = s_acc;
                int kout = s_kout;
                int t = 0;
                unsigned long long key = cand[0];
                float4 cb = bptr[(int)(~(unsigned)key)];
                while (t < C) {
                    unsigned long long nkey = 0ull;
                    float4 nb = cb;
                    if (t + 1 < C) {
                        nkey = cand[t + 1];
                        nb = bptr[(int)(~(unsigned)nkey)];
                    }
                    float sc = __uint_as_float((unsigned)(key >> 32));
                    float ca = (cb.z - cb.x) * (cb.w - cb.y);
                    bool over = false;
                    if (lane < acc) {
                        float tlx = fmaxf(rx1, cb.x);
                        float tly = fmaxf(ry1, cb.y);
                        float brx = fminf(rx2, cb.z);
                        float bry = fminf(ry2, cb.w);
                        float iw  = fmaxf(brx - tlx, 0.0f);
                        float ih  = fmaxf(bry - tly, 0.0f);
                        float inter = iw * ih;
                        float iou = inter / (rar + ca - inter);  // ref operand order
                        over = iou > 0.5f;
                    }
                    if (!__any(over)) {
                        if (lane == acc) { rx1 = cb.x; ry1 = cb.y; rx2 = cb.z; ry2 = cb.w; rar = ca; }
                        if (lane == 0) {
                            float* o = optr + (size_t)kout * 5;
                            o[0] = sc; o[1] = cb.x; o[2] = cb.y; o[3] = cb.z; o[4] = cb.w;
                        }
                        acc++; kout++;
                        if (acc == TOPK) break;
                    }
                    ++t; key = nkey; cb = nb;
                }
                if (lane == 0) { s_acc = acc; s_kout = kout; s_done = (acc == TOPK) ? 1 : 0; }
            }
            __syncthreads();
            if (s_done) break;
        }
        bin_hi = bin_lo;
    }

    __syncthreads();
    const int kout = s_kout;
    // Zero-fill remaining rows (harness poisons d_out with 0xAA every launch).
    {
        float* o  = optr + (size_t)kout * 5;
        int   rem = (TOPK - kout) * 5;
        for (int t = tid; t < rem; t += NT) o[t] = 0.0f;
    }
}

extern "C" void kernel_launch(void* const* d_in, const int* in_sizes, int n_in,
                              void* d_out, int out_size, void* d_ws, size_t ws_size,
                              hipStream_t stream) {
    const float* loc     = (const float*)d_in[0];   // [B, A, 4]
    const float* conf    = (const float*)d_in[1];   // [B, A, C]
    const float* anchors = (const float*)d_in[2];   // [A, 4]
    float* out = (float*)d_out;                     // [B, C, TOPK, 5]

    const size_t boxes_bytes  = (size_t)B_N * A_N * sizeof(float4);          // 16 MB? no: 16*16384*16 = 4 MB
    const size_t scores_bytes = (size_t)B_N * C_N * A_N * sizeof(float);     // 85 MB

    float4* boxes = (float4*)d_ws;

    decode_kernel<<<(B_N * A_N) / DNT, DNT, 0, stream>>>(
        (const float4*)loc, (const float4*)anchors, boxes);

    if (ws_size >= boxes_bytes + scores_bytes) {
        float* scoresT = (float*)((char*)d_ws + boxes_bytes);
        sigT_kernel<<<dim3(A_N / TA, B_N), TNT, 0, stream>>>(conf, scoresT);
        nms_kernel<true><<<dim3(C_N, B_N), NT, 0, stream>>>(conf, scoresT, boxes, out);
    } else {
        // fallback: proven round-4 path (strided conf reads, sigmoid in-kernel)
        nms_kernel<false><<<dim3(C_N, B_N), NT, 0, stream>>>(conf, nullptr, boxes, out);
    }
}

// Round 6
// 267.505 us; speedup vs baseline: 26.4955x; 1.4233x over previous
//
#include <hip/hip_runtime.h>
#include <math.h>

// Problem constants (from reference setup_inputs): B=16, A=16384, C=81, TOP_K=64
constexpr int B_N  = 16;
constexpr int A_N  = 16384;
constexpr int C_N  = 81;
constexpr int TOPK = 64;
constexpr int DNT  = 256;            // decode kernel block size
constexpr int NBINS = 232;           // score-bit bins covering (0.3, 1.0)
constexpr int CAP   = 512;           // candidate band capacity (pow2, 8/lane)
constexpr unsigned BIN_BASE = 0x3E99u;   // __float_as_uint(0.3f) >> 16

// transpose tile: 64 anchors x 81 classes per block
constexpr int TA   = 64;
constexpr int TNT  = 256;
constexpr int TILE_ELEMS = TA * C_N;     // 5184

// ---------------------------------------------------------------------------
// Kernel 1: SSD box decode (unchanged — bit-exact vs ref across rounds 1-5).
// ---------------------------------------------------------------------------
__global__ __launch_bounds__(DNT) void decode_kernel(const float4* __restrict__ loc,
                                                     const float4* __restrict__ anch,
                                                     float4* __restrict__ boxes) {
    int i = blockIdx.x * DNT + threadIdx.x;
    int a = i & (A_N - 1);
    float4 l  = loc[i];
    float4 an = anch[a];
    float cx = an.x + (l.x * 0.1f) * an.z;
    float cy = an.y + (l.y * 0.1f) * an.w;
    float w  = an.z * expf(l.z * 0.2f);
    float h  = an.w * expf(l.w * 0.2f);
    float x1 = cx - w * 0.5f;
    float y1 = cy - h * 0.5f;
    boxes[i] = make_float4(x1, y1, x1 + w, y1 + h);
}

// ---------------------------------------------------------------------------
// Kernel 1b: fused sigmoid + transpose (unchanged from round 5).
// ---------------------------------------------------------------------------
__global__ __launch_bounds__(TNT) void sigT_kernel(const float* __restrict__ conf,
                                                   float* __restrict__ scoresT) {
    __shared__ float tile[C_N][TA + 1];

    const int a0 = blockIdx.x * TA;
    const int b  = blockIdx.y;
    const int t  = threadIdx.x;

    const float* src = conf + ((size_t)b * A_N + a0) * C_N;
#pragma unroll
    for (int i = 0; i < (TILE_ELEMS + TNT - 1) / TNT; ++i) {
        int idx = i * TNT + t;
        if (idx < TILE_ELEMS) {
            float x = src[idx];                    // fully coalesced
            int al = idx / C_N;
            int cc = idx - al * C_N;
            tile[cc][al] = 1.0f / (1.0f + expf(-x));
        }
    }
    __syncthreads();
    float* dst = scoresT + (size_t)b * C_N * A_N + a0;
#pragma unroll
    for (int i = 0; i < (TILE_ELEMS + TNT - 1) / TNT; ++i) {
        int idx = i * TNT + t;
        if (idx < TILE_ELEMS) {
            int cc = idx >> 6;
            int al = idx & (TA - 1);
            dst[(size_t)cc * A_N + al] = tile[cc][al];
        }
    }
}

// ---------------------------------------------------------------------------
// Kernel 2: sorted-scan greedy NMS — ONE WAVE per (b,c) lane.
// Selection/suppression semantics identical to the round-4/5 kernels that
// passed (same binning, band walk w/ refill, key = (score_bits<<32)|~idx,
// same IoU operand order). Decomposition changed: 64-thread blocks, sort is
// an in-register wave bitonic (element e = r*64+lane), barriers are
// single-wave (near-free), accepted boxes live one per lane.
// ---------------------------------------------------------------------------
template <bool TRANSPOSED>
__global__ __launch_bounds__(64, 4) void nms_kernel(const float* __restrict__ conf,
                                                    const float* __restrict__ scoresT,
                                                    const float4* __restrict__ boxes,
                                                    float* __restrict__ out) {
    __shared__ int hist[NBINS];
    __shared__ unsigned long long cand[CAP];
    __shared__ int s_cnt;

    const int c    = blockIdx.x;
    const int b    = blockIdx.y;
    const int lane = threadIdx.x;          // 0..63, one wave

    for (int i = lane; i < NBINS; i += 64) hist[i] = 0;
    __syncthreads();

    const float4* bptr = boxes + (size_t)b * A_N;
    const float4* sptr = (const float4*)(scoresT + ((size_t)b * C_N + c) * A_N);
    const float*  cptr = conf + (size_t)b * A_N * C_N + c;
    float* optr = out + ((size_t)(b * C_N + c)) * TOPK * 5;

    // --- pass 1: histogram of score bits (sigmoid identical to prior rounds) ---
    for (int i = 0; i < A_N / 256; ++i) {          // 64 iterations, 4 scores each
        float s[4];
        if (TRANSPOSED) {
            float4 s4 = sptr[lane + 64 * i];       // coalesced 1KB/instr
            s[0] = s4.x; s[1] = s4.y; s[2] = s4.z; s[3] = s4.w;
        } else {
            int a0 = 4 * (lane + 64 * i);
#pragma unroll
            for (int q = 0; q < 4; ++q) {
                float x = cptr[(size_t)(a0 + q) * C_N];
                s[q] = 1.0f / (1.0f + expf(-x));
            }
        }
#pragma unroll
        for (int q = 0; q < 4; ++q) {
            if (s[q] > 0.3f) {
                unsigned u = __float_as_uint(s[q]);
                int bin = (int)(u >> 16) - (int)BIN_BASE;
                bin = bin < 0 ? 0 : (bin > NBINS - 1 ? NBINS - 1 : bin);
                atomicAdd(&hist[bin], 1);
            }
        }
    }
    __syncthreads();

    // Accepted boxes: one per lane (acc <= 64 == wave size).
    float rx1 = 0.f, ry1 = 0.f, rx2 = 0.f, ry2 = 0.f, rar = 0.f;
    int acc = 0, kout = 0;

    int bin_hi = NBINS;
    for (;;) {
        // --- band selection: redundant serial walk on all lanes (wave-uniform,
        //     LDS broadcast reads). Semantics identical to round 4/5. ---
        int lo = bin_hi, tot = 0;
        while (lo > 0) {
            int cnt = hist[lo - 1];
            if (tot + cnt > CAP) {
                if (tot == 0) { lo--; }            // single bin > CAP: take it (clamped)
                break;
            }
            tot += cnt; lo--;
        }
        const int bin_lo = lo;
        if (bin_lo == bin_hi) break;               // all bins consumed -> exhausted
        if (lane == 0) s_cnt = 0;
        __syncthreads();

        // --- pass 2: compact this band's candidates into LDS ---
        for (int i = 0; i < A_N / 256; ++i) {
            float s[4];
            if (TRANSPOSED) {
                float4 s4 = sptr[lane + 64 * i];
                s[0] = s4.x; s[1] = s4.y; s[2] = s4.z; s[3] = s4.w;
            } else {
                int a0 = 4 * (lane + 64 * i);
#pragma unroll
                for (int q = 0; q < 4; ++q) {
                    float x = cptr[(size_t)(a0 + q) * C_N];
                    s[q] = 1.0f / (1.0f + expf(-x));
                }
            }
#pragma unroll
            for (int q = 0; q < 4; ++q) {
                if (s[q] > 0.3f) {
                    unsigned u = __float_as_uint(s[q]);
                    int bin = (int)(u >> 16) - (int)BIN_BASE;
                    bin = bin < 0 ? 0 : (bin > NBINS - 1 ? NBINS - 1 : bin);
                    if (bin >= bin_lo && bin < bin_hi) {
                        int slot = atomicAdd(&s_cnt, 1);
                        if (slot < CAP) {
                            unsigned a = (unsigned)(4 * (lane + 64 * i) + q);
                            cand[slot] = ((unsigned long long)u << 32) | (unsigned)(~a);
                        }
                    }
                }
            }
        }
        __syncthreads();
        int C = s_cnt; if (C > CAP) C = CAP;

        if (C > 0) {
            // --- load into registers: element e = r*64 + lane (conflict-free) ---
            unsigned long long key[8];
#pragma unroll
            for (int r = 0; r < 8; ++r) {
                int sidx = r * 64 + lane;
                key[r] = (sidx < C) ? cand[sidx] : 0ull;   // pad: 0 < any real key
            }
            // --- wave bitonic sort, descending over e = r*64+lane ---
#pragma unroll
            for (int k = 2; k <= CAP; k <<= 1) {
#pragma unroll
                for (int j = k >> 1; j > 0; j >>= 1) {
                    if (j >= 64) {
                        int jr = j >> 6;                   // 1,2,4: in-lane pairs
#pragma unroll
                        for (int r = 0; r < 8; ++r) {
                            int rp = r ^ jr;
                            if (rp > r) {
                                int e = r * 64 + lane;
                                bool up = ((e & k) == 0);
                                unsigned long long va = key[r], vb = key[rp];
                                bool sw = up ? (va < vb) : (va > vb);
                                if (sw) { key[r] = vb; key[rp] = va; }
                            }
                        }
                    } else {                                // cross-lane via shfl
#pragma unroll
                        for (int r = 0; r < 8; ++r) {
                            int e = r * 64 + lane;
                            bool up    = ((e & k) == 0);
                            bool isLow = ((lane & j) == 0);
                            unsigned long long va = key[r];
                            unsigned long long vb = __shfl_xor(va, j, 64);
                            bool keepMax = (up == isLow);
                            key[r] = keepMax ? (va > vb ? va : vb)
                                             : (va < vb ? va : vb);
                        }
                    }
                }
            }
            // --- write sorted keys back (position e at cand[e], conflict-free) ---
            __syncthreads();
#pragma unroll
            for (int r = 0; r < 8; ++r) cand[r * 64 + lane] = key[r];
            __syncthreads();

            // --- ordered greedy scan (whole wave; accepted box #l in lane l) ---
            int t = 0;
            unsigned long long k0 = cand[0];
            float4 cb = bptr[(int)(~(unsigned)k0)];
            while (t < C) {
                unsigned long long nk = 0ull;
                float4 nb = cb;
                if (t + 1 < C) {                            // prefetch next
                    nk = cand[t + 1];
                    nb = bptr[(int)(~(unsigned)nk)];
                }
                float sc = __uint_as_float((unsigned)(k0 >> 32));
                float ca = (cb.z - cb.x) * (cb.w - cb.y);
                bool over = false;
                if (lane < acc) {
                    float tlx = fmaxf(rx1, cb.x);
                    float tly = fmaxf(ry1, cb.y);
                    float brx = fminf(rx2, cb.z);
                    float bry = fminf(ry2, cb.w);
                    float iw  = fmaxf(brx - tlx, 0.0f);
                    float ih  = fmaxf(bry - tly, 0.0f);
                    float inter = iw * ih;
                    float iou = inter / (rar + ca - inter); // ref operand order
                    over = iou > 0.5f;
                }
                if (!__any(over)) {
                    if (lane == acc) { rx1 = cb.x; ry1 = cb.y; rx2 = cb.z; ry2 = cb.w; rar = ca; }
                    if (lane == 0) {
                        float* o = optr + (size_t)kout * 5;
                        o[0] = sc; o[1] = cb.x; o[2] = cb.y; o[3] = cb.z; o[4] = cb.w;
                    }
                    acc++; kout++;                          // wave-uniform
                    if (acc == TOPK) break;
                }
                ++t; k0 = nk; cb = nb;
            }
        }
        if (acc == TOPK) break;
        bin_hi = bin_lo;
    }

    // Zero-fill remaining rows (harness poisons d_out with 0xAA every launch).
    {
        float* o  = optr + (size_t)kout * 5;
        int   rem = (TOPK - kout) * 5;
        for (int t = lane; t < rem; t += 64) o[t] = 0.0f;
    }
}

extern "C" void kernel_launch(void* const* d_in, const int* in_sizes, int n_in,
                              void* d_out, int out_size, void* d_ws, size_t ws_size,
                              hipStream_t stream) {
    const float* loc     = (const float*)d_in[0];   // [B, A, 4]
    const float* conf    = (const float*)d_in[1];   // [B, A, C]
    const float* anchors = (const float*)d_in[2];   // [A, 4]
    float* out = (float*)d_out;                     // [B, C, TOPK, 5]

    const size_t boxes_bytes  = (size_t)B_N * A_N * sizeof(float4);          // 4 MB
    const size_t scores_bytes = (size_t)B_N * C_N * A_N * sizeof(float);     // 85 MB

    float4* boxes = (float4*)d_ws;

    decode_kernel<<<(B_N * A_N) / DNT, DNT, 0, stream>>>(
        (const float4*)loc, (const float4*)anchors, boxes);

    if (ws_size >= boxes_bytes + scores_bytes) {
        float* scoresT = (float*)((char*)d_ws + boxes_bytes);
        sigT_kernel<<<dim3(A_N / TA, B_N), TNT, 0, stream>>>(conf, scoresT);
        nms_kernel<true><<<dim3(C_N, B_N), 64, 0, stream>>>(conf, scoresT, boxes, out);
    } else {
        // fallback: strided conf reads, sigmoid in-kernel (proven semantics)
        nms_kernel<false><<<dim3(C_N, B_N), 64, 0, stream>>>(conf, nullptr, boxes, out);
    }
}

// Round 7
// 254.343 us; speedup vs baseline: 27.8666x; 1.0518x over previous
//
#include <hip/hip_runtime.h>
#include <math.h>

// Problem constants (from reference setup_inputs): B=16, A=16384, C=81, TOP_K=64
constexpr int B_N  = 16;
constexpr int A_N  = 16384;
constexpr int C_N  = 81;
constexpr int TOPK = 64;
constexpr int DNT  = 256;            // decode kernel block size
constexpr int NBINS = 232;           // score-bit bins covering (0.3, 1.0)
constexpr int CAP   = 512;           // candidate band capacity (pow2, 8/lane)
constexpr unsigned BIN_BASE = 0x3E99u;   // __float_as_uint(0.3f) >> 16

// sigmoid+transpose tile: 128 anchors x 81 classes per block
constexpr int TA   = 128;
constexpr int TPAD = 85;                 // tile row stride (floats), conflict-mitigating
constexpr int TNT  = 256;
constexpr int TILE_ELEMS = TA * C_N;     // 10368
constexpr int TILE_F4    = (TA / 4) * C_N; // 2592 float4 stores per tile

constexpr int HNT = 256;             // histogram kernel block size

// ---------------------------------------------------------------------------
// Kernel 1: SSD box decode (unchanged — bit-exact vs ref across rounds 1-6).
// ---------------------------------------------------------------------------
__global__ __launch_bounds__(DNT) void decode_kernel(const float4* __restrict__ loc,
                                                     const float4* __restrict__ anch,
                                                     float4* __restrict__ boxes) {
    int i = blockIdx.x * DNT + threadIdx.x;
    int a = i & (A_N - 1);
    float4 l  = loc[i];
    float4 an = anch[a];
    float cx = an.x + (l.x * 0.1f) * an.z;
    float cy = an.y + (l.y * 0.1f) * an.w;
    float w  = an.z * expf(l.z * 0.2f);
    float h  = an.w * expf(l.w * 0.2f);
    float x1 = cx - w * 0.5f;
    float y1 = cy - h * 0.5f;
    boxes[i] = make_float4(x1, y1, x1 + w, y1 + h);
}

// ---------------------------------------------------------------------------
// Kernel 1b: fused sigmoid + transpose, v2. conf[b,a,c] -> scores_T[b,c,a].
// TA=128 anchors/block; tile[al][cc] layout (phase-1 writes conflict-free);
// phase-2 emits float4 stores (16 B/lane vs round-6's 4 B/lane).
// Sigmoid expression identical to all passing rounds; values bit-identical.
// ---------------------------------------------------------------------------
__global__ __launch_bounds__(TNT) void sigT_kernel(const float* __restrict__ conf,
                                                   float* __restrict__ scoresT) {
    __shared__ float tile[TA][TPAD];

    const int a0 = blockIdx.x * TA;
    const int b  = blockIdx.y;
    const int t  = threadIdx.x;

    const float* src = conf + ((size_t)b * A_N + a0) * C_N;
#pragma unroll
    for (int i = 0; i < (TILE_ELEMS + TNT - 1) / TNT; ++i) {
        int idx = i * TNT + t;
        if (idx < TILE_ELEMS) {
            float x  = src[idx];                   // fully coalesced
            int   al = idx / C_N;
            int   cc = idx - al * C_N;
            tile[al][cc] = 1.0f / (1.0f + expf(-x));
        }
    }
    __syncthreads();
    float* dst = scoresT + (size_t)b * C_N * A_N + a0;
#pragma unroll
    for (int i = 0; i < (TILE_F4 + TNT - 1) / TNT; ++i) {
        int idx4 = i * TNT + t;
        if (idx4 < TILE_F4) {
            int cc  = idx4 >> 5;                   // 32 float4 per class row
            int al4 = idx4 & 31;
            float4 v;
            v.x = tile[al4 * 4 + 0][cc];
            v.y = tile[al4 * 4 + 1][cc];
            v.z = tile[al4 * 4 + 2][cc];
            v.w = tile[al4 * 4 + 3][cc];
            ((float4*)(dst + (size_t)cc * A_N))[al4] = v;   // dwordx4 stores
        }
    }
}

// ---------------------------------------------------------------------------
// Kernel 1c: per-(b,c) score histogram, one block per (b,c), 20 waves/CU of
// TLP (vs computing it on the single nms wave). Reads the SAME stored score
// values the compact pass reads -> hist/compact consistent by construction.
// Bin formula identical to rounds 4-6. Plain stores (no global atomics).
// ---------------------------------------------------------------------------
__global__ __launch_bounds__(HNT) void hist_kernel(const float* __restrict__ scoresT,
                                                   int* __restrict__ ghist) {
    __shared__ int hist[NBINS];
    const int bc = blockIdx.x;
    const int t  = threadIdx.x;
    for (int i = t; i < NBINS; i += HNT) hist[i] = 0;
    __syncthreads();
    const float4* sptr = (const float4*)(scoresT + (size_t)bc * A_N);
    for (int i = 0; i < A_N / 4 / HNT; ++i) {      // 16 iterations
        float4 s4 = sptr[t + HNT * i];
        float s[4] = {s4.x, s4.y, s4.z, s4.w};
#pragma unroll
        for (int q = 0; q < 4; ++q) {
            if (s[q] > 0.3f) {
                unsigned u = __float_as_uint(s[q]);
                int bin = (int)(u >> 16) - (int)BIN_BASE;
                bin = bin < 0 ? 0 : (bin > NBINS - 1 ? NBINS - 1 : bin);
                atomicAdd(&hist[bin], 1);
            }
        }
    }
    __syncthreads();
    int* g = ghist + (size_t)bc * NBINS;
    for (int i = t; i < NBINS; i += HNT) g[i] = hist[i];
}

// ---------------------------------------------------------------------------
// Kernel 2: sorted-scan greedy NMS — one wave per (b,c). Semantics identical
// to rounds 4-6 (band walk w/ refill, key=(score_bits<<32)|~idx, wave bitonic,
// same IoU operand order). New: hist is preloaded from ghist, and the sorted
// band's boxes are GATHERED INTO LDS (64-wide parallel) so the serial scan
// pays LDS-broadcast latency instead of per-candidate L2 latency.
// ---------------------------------------------------------------------------
template <bool TRANSPOSED>
__global__ __launch_bounds__(64, 4) void nms_kernel(const float* __restrict__ conf,
                                                    const float* __restrict__ scoresT,
                                                    const int* __restrict__ ghist,
                                                    const float4* __restrict__ boxes,
                                                    float* __restrict__ out) {
    __shared__ int hist[NBINS];
    __shared__ unsigned long long cand[CAP];
    __shared__ float4 cbox[CAP];
    __shared__ int s_cnt;

    const int c    = blockIdx.x;
    const int b    = blockIdx.y;
    const int lane = threadIdx.x;          // 0..63, one wave

    const float4* bptr = boxes + (size_t)b * A_N;
    const float4* sptr = (const float4*)(scoresT + ((size_t)b * C_N + c) * A_N);
    const float*  cptr = conf + (size_t)b * A_N * C_N + c;
    float* optr = out + ((size_t)(b * C_N + c)) * TOPK * 5;

    if (TRANSPOSED) {
        const int* g = ghist + (size_t)(b * C_N + c) * NBINS;
        for (int i = lane; i < NBINS; i += 64) hist[i] = g[i];
    } else {
        for (int i = lane; i < NBINS; i += 64) hist[i] = 0;
        __syncthreads();
        for (int i = 0; i < A_N / 256; ++i) {
            int a0 = 4 * (lane + 64 * i);
#pragma unroll
            for (int q = 0; q < 4; ++q) {
                float x = cptr[(size_t)(a0 + q) * C_N];
                float s = 1.0f / (1.0f + expf(-x));
                if (s > 0.3f) {
                    unsigned u = __float_as_uint(s);
                    int bin = (int)(u >> 16) - (int)BIN_BASE;
                    bin = bin < 0 ? 0 : (bin > NBINS - 1 ? NBINS - 1 : bin);
                    atomicAdd(&hist[bin], 1);
                }
            }
        }
    }
    __syncthreads();

    // Accepted boxes: one per lane (acc <= 64 == wave size).
    float rx1 = 0.f, ry1 = 0.f, rx2 = 0.f, ry2 = 0.f, rar = 0.f;
    int acc = 0, kout = 0;

    int bin_hi = NBINS;
    for (;;) {
        // --- band selection: redundant serial walk, wave-uniform LDS reads ---
        int lo = bin_hi, tot = 0;
        while (lo > 0) {
            int cnt = hist[lo - 1];
            if (tot + cnt > CAP) {
                if (tot == 0) { lo--; }            // single bin > CAP: take it (clamped)
                break;
            }
            tot += cnt; lo--;
        }
        const int bin_lo = lo;
        if (bin_lo == bin_hi) break;               // all bins consumed -> exhausted
        if (lane == 0) s_cnt = 0;
        __syncthreads();

        // --- compact this band's candidates into LDS ---
        for (int i = 0; i < A_N / 256; ++i) {
            float s[4];
            if (TRANSPOSED) {
                float4 s4 = sptr[lane + 64 * i];
                s[0] = s4.x; s[1] = s4.y; s[2] = s4.z; s[3] = s4.w;
            } else {
                int a0 = 4 * (lane + 64 * i);
#pragma unroll
                for (int q = 0; q < 4; ++q) {
                    float x = cptr[(size_t)(a0 + q) * C_N];
                    s[q] = 1.0f / (1.0f + expf(-x));
                }
            }
#pragma unroll
            for (int q = 0; q < 4; ++q) {
                if (s[q] > 0.3f) {
                    unsigned u = __float_as_uint(s[q]);
                    int bin = (int)(u >> 16) - (int)BIN_BASE;
                    bin = bin < 0 ? 0 : (bin > NBINS - 1 ? NBINS - 1 : bin);
                    if (bin >= bin_lo && bin < bin_hi) {
                        int slot = atomicAdd(&s_cnt, 1);
                        if (slot < CAP) {
                            unsigned a = (unsigned)(4 * (lane + 64 * i) + q);
                            cand[slot] = ((unsigned long long)u << 32) | (unsigned)(~a);
                        }
                    }
                }
            }
        }
        __syncthreads();
        int C = s_cnt; if (C > CAP) C = CAP;

        if (C > 0) {
            // --- load into registers: element e = r*64 + lane ---
            unsigned long long key[8];
#pragma unroll
            for (int r = 0; r < 8; ++r) {
                int sidx = r * 64 + lane;
                key[r] = (sidx < C) ? cand[sidx] : 0ull;   // pad: 0 < any real key
            }
            // --- wave bitonic sort, descending over e = r*64+lane ---
#pragma unroll
            for (int k = 2; k <= CAP; k <<= 1) {
#pragma unroll
                for (int j = k >> 1; j > 0; j >>= 1) {
                    if (j >= 64) {
                        int jr = j >> 6;                   // 1,2,4: in-lane pairs
#pragma unroll
                        for (int r = 0; r < 8; ++r) {
                            int rp = r ^ jr;
                            if (rp > r) {
                                int e = r * 64 + lane;
                                bool up = ((e & k) == 0);
                                unsigned long long va = key[r], vb = key[rp];
                                bool sw = up ? (va < vb) : (va > vb);
                                if (sw) { key[r] = vb; key[rp] = va; }
                            }
                        }
                    } else {                                // cross-lane via shfl
#pragma unroll
                        for (int r = 0; r < 8; ++r) {
                            int e = r * 64 + lane;
                            bool up    = ((e & k) == 0);
                            bool isLow = ((lane & j) == 0);
                            unsigned long long va = key[r];
                            unsigned long long vb = __shfl_xor(va, j, 64);
                            bool keepMax = (up == isLow);
                            key[r] = keepMax ? (va > vb ? va : vb)
                                             : (va < vb ? va : vb);
                        }
                    }
                }
            }
            __syncthreads();
#pragma unroll
            for (int r = 0; r < 8; ++r) cand[r * 64 + lane] = key[r];
            __syncthreads();

            // --- gather candidate boxes into LDS (64-wide parallel) ---
#pragma unroll
            for (int r = 0; r < 8; ++r) {
                int e = r * 64 + lane;
                if (e < C) {
                    int idx = (int)(~(unsigned)cand[e]);
                    cbox[e] = bptr[idx];
                }
            }
            __syncthreads();

            // --- ordered greedy scan: candidates from LDS, 1-deep prefetch ---
            int t = 0;
            unsigned long long k0 = cand[0];
            float4 cb = cbox[0];
            while (t < C) {
                unsigned long long nk = 0ull;
                float4 nb = cb;
                if (t + 1 < C) { nk = cand[t + 1]; nb = cbox[t + 1]; }
                float sc = __uint_as_float((unsigned)(k0 >> 32));
                float ca = (cb.z - cb.x) * (cb.w - cb.y);
                bool over = false;
                if (lane < acc) {
                    float tlx = fmaxf(rx1, cb.x);
                    float tly = fmaxf(ry1, cb.y);
                    float brx = fminf(rx2, cb.z);
                    float bry = fminf(ry2, cb.w);
                    float iw  = fmaxf(brx - tlx, 0.0f);
                    float ih  = fmaxf(bry - tly, 0.0f);
                    float inter = iw * ih;
                    float iou = inter / (rar + ca - inter); // ref operand order
                    over = iou > 0.5f;
                }
                if (!__any(over)) {
                    if (lane == acc) { rx1 = cb.x; ry1 = cb.y; rx2 = cb.z; ry2 = cb.w; rar = ca; }
                    if (lane == 0) {
                        float* o = optr + (size_t)kout * 5;
                        o[0] = sc; o[1] = cb.x; o[2] = cb.y; o[3] = cb.z; o[4] = cb.w;
                    }
                    acc++; kout++;                          // wave-uniform
                    if (acc == TOPK) break;
                }
                ++t; k0 = nk; cb = nb;
            }
        }
        if (acc == TOPK) break;
        bin_hi = bin_lo;
    }

    // Zero-fill remaining rows (harness poisons d_out with 0xAA every launch).
    {
        float* o  = optr + (size_t)kout * 5;
        int   rem = (TOPK - kout) * 5;
        for (int t = lane; t < rem; t += 64) o[t] = 0.0f;
    }
}

extern "C" void kernel_launch(void* const* d_in, const int* in_sizes, int n_in,
                              void* d_out, int out_size, void* d_ws, size_t ws_size,
                              hipStream_t stream) {
    const float* loc     = (const float*)d_in[0];   // [B, A, 4]
    const float* conf    = (const float*)d_in[1];   // [B, A, C]
    const float* anchors = (const float*)d_in[2];   // [A, 4]
    float* out = (float*)d_out;                     // [B, C, TOPK, 5]

    const size_t boxes_bytes  = (size_t)B_N * A_N * sizeof(float4);          // 4 MB
    const size_t scores_bytes = (size_t)B_N * C_N * A_N * sizeof(float);     // 85 MB
    const size_t hist_bytes   = (size_t)B_N * C_N * NBINS * sizeof(int);     // 1.2 MB

    float4* boxes = (float4*)d_ws;

    decode_kernel<<<(B_N * A_N) / DNT, DNT, 0, stream>>>(
        (const float4*)loc, (const float4*)anchors, boxes);

    if (ws_size >= boxes_bytes + scores_bytes + hist_bytes) {
        float* scoresT = (float*)((char*)d_ws + boxes_bytes);
        int*   ghist   = (int*)((char*)d_ws + boxes_bytes + scores_bytes);
        sigT_kernel<<<dim3(A_N / TA, B_N), TNT, 0, stream>>>(conf, scoresT);
        hist_kernel<<<dim3(B_N * C_N), HNT, 0, stream>>>(scoresT, ghist);
        nms_kernel<true><<<dim3(C_N, B_N), 64, 0, stream>>>(conf, scoresT, ghist, boxes, out);
    } else {
        // fallback: strided conf reads, in-wave histogram (proven semantics)
        nms_kernel<false><<<dim3(C_N, B_N), 64, 0, stream>>>(conf, nullptr, nullptr, boxes, out);
    }
}

// Round 8
// 224.681 us; speedup vs baseline: 31.5455x; 1.1320x over previous
//
#include <hip/hip_runtime.h>
#include <math.h>

// Problem constants (from reference setup_inputs): B=16, A=16384, C=81, TOP_K=64
constexpr int B_N  = 16;
constexpr int A_N  = 16384;
constexpr int C_N  = 81;
constexpr int TOPK = 64;
constexpr int DNT  = 256;            // decode kernel block size
constexpr int NBINS = 232;           // score-bit bins covering (0.3, 1.0)
constexpr int CAP   = 512;           // candidate band capacity (pow2, 8/lane)
constexpr unsigned BIN_BASE = 0x3E99u;   // __float_as_uint(0.3f) >> 16

// sigmoid+transpose tile: 128 anchors x 81 classes per block
constexpr int TA   = 128;
constexpr int TPAD = 85;
constexpr int TNT  = 256;
constexpr int TILE_ELEMS = TA * C_N;       // 10368
constexpr int TILE_F4    = (TA / 4) * C_N; // 2592 float4 stores per tile

constexpr int SNT = 256;             // select kernel block size

// ---------------------------------------------------------------------------
// Kernel 1: SSD box decode (unchanged — bit-exact vs ref across rounds 1-7).
// ---------------------------------------------------------------------------
__global__ __launch_bounds__(DNT) void decode_kernel(const float4* __restrict__ loc,
                                                     const float4* __restrict__ anch,
                                                     float4* __restrict__ boxes) {
    int i = blockIdx.x * DNT + threadIdx.x;
    int a = i & (A_N - 1);
    float4 l  = loc[i];
    float4 an = anch[a];
    float cx = an.x + (l.x * 0.1f) * an.z;
    float cy = an.y + (l.y * 0.1f) * an.w;
    float w  = an.z * expf(l.z * 0.2f);
    float h  = an.w * expf(l.w * 0.2f);
    float x1 = cx - w * 0.5f;
    float y1 = cy - h * 0.5f;
    boxes[i] = make_float4(x1, y1, x1 + w, y1 + h);
}

// ---------------------------------------------------------------------------
// Kernel 1b: fused sigmoid + transpose (unchanged from round 7).
// ---------------------------------------------------------------------------
__global__ __launch_bounds__(TNT) void sigT_kernel(const float* __restrict__ conf,
                                                   float* __restrict__ scoresT) {
    __shared__ float tile[TA][TPAD];

    const int a0 = blockIdx.x * TA;
    const int b  = blockIdx.y;
    const int t  = threadIdx.x;

    const float* src = conf + ((size_t)b * A_N + a0) * C_N;
#pragma unroll
    for (int i = 0; i < (TILE_ELEMS + TNT - 1) / TNT; ++i) {
        int idx = i * TNT + t;
        if (idx < TILE_ELEMS) {
            float x  = src[idx];                   // fully coalesced
            int   al = idx / C_N;
            int   cc = idx - al * C_N;
            tile[al][cc] = 1.0f / (1.0f + expf(-x));
        }
    }
    __syncthreads();
    float* dst = scoresT + (size_t)b * C_N * A_N + a0;
#pragma unroll
    for (int i = 0; i < (TILE_F4 + TNT - 1) / TNT; ++i) {
        int idx4 = i * TNT + t;
        if (idx4 < TILE_F4) {
            int cc  = idx4 >> 5;                   // 32 float4 per class row
            int al4 = idx4 & 31;
            float4 v;
            v.x = tile[al4 * 4 + 0][cc];
            v.y = tile[al4 * 4 + 1][cc];
            v.z = tile[al4 * 4 + 2][cc];
            v.w = tile[al4 * 4 + 3][cc];
            ((float4*)(dst + (size_t)cc * A_N))[al4] = v;   // dwordx4 stores
        }
    }
}

// ---------------------------------------------------------------------------
// Kernel 1c: SELECT — per-(b,c) histogram + first-band compaction, one block
// per (b,c) at 20 waves/CU (vs doing the compact on the single nms wave at
// ~4 waves/CU in round 7). Bin formula + band walk verbatim from rounds 4-7.
// Key SET is identical to the in-nms compact (arrival order differs; the
// full bitonic sort in nms canonicalizes order). Writes ghist for refills.
// ---------------------------------------------------------------------------
__global__ __launch_bounds__(SNT) void select_kernel(const float* __restrict__ scoresT,
                                                     int* __restrict__ ghist,
                                                     unsigned long long* __restrict__ gcand,
                                                     int2* __restrict__ gmeta) {
    __shared__ int hist[NBINS];
    __shared__ int s_cnt;
    const int bc = blockIdx.x;
    const int t  = threadIdx.x;
    for (int i = t; i < NBINS; i += SNT) hist[i] = 0;
    __syncthreads();

    const float4* sptr = (const float4*)(scoresT + (size_t)bc * A_N);
    // --- pass 1: histogram ---
    for (int i = 0; i < A_N / 4 / SNT; ++i) {      // 16 iterations
        float4 s4 = sptr[t + SNT * i];
        float s[4] = {s4.x, s4.y, s4.z, s4.w};
#pragma unroll
        for (int q = 0; q < 4; ++q) {
            if (s[q] > 0.3f) {
                unsigned u = __float_as_uint(s[q]);
                int bin = (int)(u >> 16) - (int)BIN_BASE;
                bin = bin < 0 ? 0 : (bin > NBINS - 1 ? NBINS - 1 : bin);
                atomicAdd(&hist[bin], 1);
            }
        }
    }
    __syncthreads();
    int* g = ghist + (size_t)bc * NBINS;
    for (int i = t; i < NBINS; i += SNT) g[i] = hist[i];

    // --- band walk (redundant on all threads; wave-uniform LDS reads) ---
    int lo = NBINS, tot = 0;
    while (lo > 0) {
        int cnt = hist[lo - 1];
        if (tot + cnt > CAP) {
            if (tot == 0) { lo--; }                // single bin > CAP: take it (clamped)
            break;
        }
        tot += cnt; lo--;
    }
    if (t == 0) s_cnt = 0;
    __syncthreads();

    // --- pass 2: compact first band (bin in [lo, NBINS)) ---
    unsigned long long* cd = gcand + (size_t)bc * CAP;
    for (int i = 0; i < A_N / 4 / SNT; ++i) {
        float4 s4 = sptr[t + SNT * i];
        float s[4] = {s4.x, s4.y, s4.z, s4.w};
#pragma unroll
        for (int q = 0; q < 4; ++q) {
            if (s[q] > 0.3f) {
                unsigned u = __float_as_uint(s[q]);
                int bin = (int)(u >> 16) - (int)BIN_BASE;
                bin = bin < 0 ? 0 : (bin > NBINS - 1 ? NBINS - 1 : bin);
                if (bin >= lo) {
                    int slot = atomicAdd(&s_cnt, 1);
                    if (slot < CAP) {
                        unsigned a = (unsigned)(4 * (t + SNT * i) + q);
                        cd[slot] = ((unsigned long long)u << 32) | (unsigned)(~a);
                    }
                }
            }
        }
    }
    __syncthreads();
    if (t == 0) {
        int C = s_cnt; if (C > CAP) C = CAP;
        gmeta[bc] = make_int2(C, lo);
    }
}

// ---------------------------------------------------------------------------
// sort + box-gather + ordered scan over one band in LDS. Verbatim round-7
// logic (wave bitonic over e=r*64+lane, LDS box gather, 1-deep prefetch scan).
// Accepted-box state persists across calls via refs.
// ---------------------------------------------------------------------------
__device__ __forceinline__ void sort_gather_scan(
        unsigned long long* cand, float4* cbox, int C, int lane,
        const float4* __restrict__ bptr, float* __restrict__ optr,
        float& rx1, float& ry1, float& rx2, float& ry2, float& rar,
        int& acc, int& kout) {
    unsigned long long key[8];
#pragma unroll
    for (int r = 0; r < 8; ++r) {
        int sidx = r * 64 + lane;
        key[r] = (sidx < C) ? cand[sidx] : 0ull;   // pad: 0 < any real key
    }
#pragma unroll
    for (int k = 2; k <= CAP; k <<= 1) {
#pragma unroll
        for (int j = k >> 1; j > 0; j >>= 1) {
            if (j >= 64) {
                int jr = j >> 6;                   // 1,2,4: in-lane pairs
#pragma unroll
                for (int r = 0; r < 8; ++r) {
                    int rp = r ^ jr;
                    if (rp > r) {
                        int e = r * 64 + lane;
                        bool up = ((e & k) == 0);
                        unsigned long long va = key[r], vb = key[rp];
                        bool sw = up ? (va < vb) : (va > vb);
                        if (sw) { key[r] = vb; key[rp] = va; }
                    }
                }
            } else {                                // cross-lane via shfl
#pragma unroll
                for (int r = 0; r < 8; ++r) {
                    int e = r * 64 + lane;
                    bool up    = ((e & k) == 0);
                    bool isLow = ((lane & j) == 0);
                    unsigned long long va = key[r];
                    unsigned long long vb = __shfl_xor(va, j, 64);
                    bool keepMax = (up == isLow);
                    key[r] = keepMax ? (va > vb ? va : vb)
                                     : (va < vb ? va : vb);
                }
            }
        }
    }
    __syncthreads();
#pragma unroll
    for (int r = 0; r < 8; ++r) cand[r * 64 + lane] = key[r];
    __syncthreads();
#pragma unroll
    for (int r = 0; r < 8; ++r) {
        int e = r * 64 + lane;
        if (e < C) cbox[e] = bptr[(int)(~(unsigned)cand[e])];
    }
    __syncthreads();

    int t = 0;
    unsigned long long k0 = cand[0];
    float4 cb = cbox[0];
    while (t < C) {
        unsigned long long nk = 0ull;
        float4 nb = cb;
        if (t + 1 < C) { nk = cand[t + 1]; nb = cbox[t + 1]; }
        float sc = __uint_as_float((unsigned)(k0 >> 32));
        float ca = (cb.z - cb.x) * (cb.w - cb.y);
        bool over = false;
        if (lane < acc) {
            float tlx = fmaxf(rx1, cb.x);
            float tly = fmaxf(ry1, cb.y);
            float brx = fminf(rx2, cb.z);
            float bry = fminf(ry2, cb.w);
            float iw  = fmaxf(brx - tlx, 0.0f);
            float ih  = fmaxf(bry - tly, 0.0f);
            float inter = iw * ih;
            float iou = inter / (rar + ca - inter); // ref operand order
            over = iou > 0.5f;
        }
        if (!__any(over)) {
            if (lane == acc) { rx1 = cb.x; ry1 = cb.y; rx2 = cb.z; ry2 = cb.w; rar = ca; }
            if (lane == 0) {
                float* o = optr + (size_t)kout * 5;
                o[0] = sc; o[1] = cb.x; o[2] = cb.y; o[3] = cb.z; o[4] = cb.w;
            }
            acc++; kout++;                          // wave-uniform
            if (acc == TOPK) break;
        }
        ++t; k0 = nk; cb = nb;
    }
}

// ---------------------------------------------------------------------------
// Kernel 2: NMS finisher — one wave per (b,c). PRESEL: first band comes
// precompacted from select_kernel; refill path (rare) is verbatim round-7
// band walk + compact from scoresT. Non-PRESEL fallback: round-6/7 standalone
// (strided conf, in-wave hist) — proven semantics.
// ---------------------------------------------------------------------------
template <bool PRESEL>
__global__ __launch_bounds__(64, 4) void nms_kernel(const float* __restrict__ conf,
                                                    const float* __restrict__ scoresT,
                                                    const int* __restrict__ ghist,
                                                    const unsigned long long* __restrict__ gcand,
                                                    const int2* __restrict__ gmeta,
                                                    const float4* __restrict__ boxes,
                                                    float* __restrict__ out) {
    __shared__ int hist[NBINS];
    __shared__ unsigned long long cand[CAP];
    __shared__ float4 cbox[CAP];
    __shared__ int s_cnt;

    const int c    = blockIdx.x;
    const int b    = blockIdx.y;
    const int bc   = b * C_N + c;
    const int lane = threadIdx.x;          // 0..63, one wave

    const float4* bptr = boxes + (size_t)b * A_N;
    const float4* sptr = (const float4*)(scoresT + (size_t)bc * A_N);
    const float*  cptr = conf + (size_t)b * A_N * C_N + c;
    float* optr = out + (size_t)bc * TOPK * 5;

    float rx1 = 0.f, ry1 = 0.f, rx2 = 0.f, ry2 = 0.f, rar = 0.f;
    int acc = 0, kout = 0;
    int bin_hi;

    if (PRESEL) {
        int2 meta = gmeta[bc];
        int C = meta.x;
        bin_hi = meta.y;                   // next band starts below first band
        const unsigned long long* cd = gcand + (size_t)bc * CAP;
#pragma unroll
        for (int r = 0; r < 8; ++r) {
            int e = r * 64 + lane;
            cand[e] = (e < C) ? cd[e] : 0ull;
        }
        __syncthreads();
        if (C > 0)
            sort_gather_scan(cand, cbox, C, lane, bptr, optr,
                             rx1, ry1, rx2, ry2, rar, acc, kout);
        if (acc < TOPK && bin_hi > 0) {    // rare refill: need hist
            for (int i = lane; i < NBINS; i += 64) hist[i] = ghist[(size_t)bc * NBINS + i];
            __syncthreads();
        }
    } else {
        // standalone: in-wave histogram from strided conf (proven fallback)
        for (int i = lane; i < NBINS; i += 64) hist[i] = 0;
        __syncthreads();
        for (int i = 0; i < A_N / 256; ++i) {
            int a0 = 4 * (lane + 64 * i);
#pragma unroll
            for (int q = 0; q < 4; ++q) {
                float x = cptr[(size_t)(a0 + q) * C_N];
                float s = 1.0f / (1.0f + expf(-x));
                if (s > 0.3f) {
                    unsigned u = __float_as_uint(s);
                    int bin = (int)(u >> 16) - (int)BIN_BASE;
                    bin = bin < 0 ? 0 : (bin > NBINS - 1 ? NBINS - 1 : bin);
                    atomicAdd(&hist[bin], 1);
                }
            }
        }
        __syncthreads();
        bin_hi = NBINS;
    }

    // --- band loop (first band already consumed in PRESEL mode) ---
    while (acc < TOPK) {
        int lo = bin_hi, tot = 0;
        while (lo > 0) {
            int cnt = hist[lo - 1];
            if (tot + cnt > CAP) {
                if (tot == 0) { lo--; }            // single bin > CAP: take it (clamped)
                break;
            }
            tot += cnt; lo--;
        }
        const int bin_lo = lo;
        if (bin_lo == bin_hi) break;               // exhausted
        if (lane == 0) s_cnt = 0;
        __syncthreads();

        for (int i = 0; i < A_N / 256; ++i) {
            float s[4];
            if (PRESEL) {
                float4 s4 = sptr[lane + 64 * i];
                s[0] = s4.x; s[1] = s4.y; s[2] = s4.z; s[3] = s4.w;
            } else {
                int a0 = 4 * (lane + 64 * i);
#pragma unroll
                for (int q = 0; q < 4; ++q) {
                    float x = cptr[(size_t)(a0 + q) * C_N];
                    s[q] = 1.0f / (1.0f + expf(-x));
                }
            }
#pragma unroll
            for (int q = 0; q < 4; ++q) {
                if (s[q] > 0.3f) {
                    unsigned u = __float_as_uint(s[q]);
                    int bin = (int)(u >> 16) - (int)BIN_BASE;
                    bin = bin < 0 ? 0 : (bin > NBINS - 1 ? NBINS - 1 : bin);
                    if (bin >= bin_lo && bin < bin_hi) {
                        int slot = atomicAdd(&s_cnt, 1);
                        if (slot < CAP) {
                            unsigned a = (unsigned)(4 * (lane + 64 * i) + q);
                            cand[slot] = ((unsigned long long)u << 32) | (unsigned)(~a);
                        }
                    }
                }
            }
        }
        __syncthreads();
        int C = s_cnt; if (C > CAP) C = CAP;
        if (C > 0)
            sort_gather_scan(cand, cbox, C, lane, bptr, optr,
                             rx1, ry1, rx2, ry2, rar, acc, kout);
        bin_hi = bin_lo;
    }

    // Zero-fill remaining rows (harness poisons d_out with 0xAA every launch).
    {
        float* o  = optr + (size_t)kout * 5;
        int   rem = (TOPK - kout) * 5;
        for (int t = lane; t < rem; t += 64) o[t] = 0.0f;
    }
}

extern "C" void kernel_launch(void* const* d_in, const int* in_sizes, int n_in,
                              void* d_out, int out_size, void* d_ws, size_t ws_size,
                              hipStream_t stream) {
    const float* loc     = (const float*)d_in[0];   // [B, A, 4]
    const float* conf    = (const float*)d_in[1];   // [B, A, C]
    const float* anchors = (const float*)d_in[2];   // [A, 4]
    float* out = (float*)d_out;                     // [B, C, TOPK, 5]

    const size_t boxes_bytes  = (size_t)B_N * A_N * sizeof(float4);               // 4 MB
    const size_t scores_bytes = (size_t)B_N * C_N * A_N * sizeof(float);          // 85 MB
    const size_t hist_bytes   = (size_t)B_N * C_N * NBINS * sizeof(int);          // 1.2 MB
    const size_t cand_bytes   = (size_t)B_N * C_N * CAP * sizeof(unsigned long long); // 5.3 MB
    const size_t meta_bytes   = (size_t)B_N * C_N * sizeof(int2);

    float4* boxes = (float4*)d_ws;

    decode_kernel<<<(B_N * A_N) / DNT, DNT, 0, stream>>>(
        (const float4*)loc, (const float4*)anchors, boxes);

    if (ws_size >= boxes_bytes + scores_bytes + hist_bytes + cand_bytes + meta_bytes) {
        char* p = (char*)d_ws + boxes_bytes;
        float* scoresT            = (float*)p;              p += scores_bytes;
        int*   ghist              = (int*)p;                p += hist_bytes;
        unsigned long long* gcand = (unsigned long long*)p; p += cand_bytes;
        int2*  gmeta              = (int2*)p;
        sigT_kernel<<<dim3(A_N / TA, B_N), TNT, 0, stream>>>(conf, scoresT);
        select_kernel<<<dim3(B_N * C_N), SNT, 0, stream>>>(scoresT, ghist, gcand, gmeta);
        nms_kernel<true><<<dim3(C_N, B_N), 64, 0, stream>>>(conf, scoresT, ghist, gcand, gmeta, boxes, out);
    } else {
        // fallback: strided conf reads, in-wave histogram (proven semantics)
        nms_kernel<false><<<dim3(C_N, B_N), 64, 0, stream>>>(conf, nullptr, nullptr, nullptr, nullptr, boxes, out);
    }
}

// Round 9
// 220.746 us; speedup vs baseline: 32.1079x; 1.0178x over previous
//
#include <hip/hip_runtime.h>
#include <math.h>

// Problem constants (from reference setup_inputs): B=16, A=16384, C=81, TOP_K=64
constexpr int B_N  = 16;
constexpr int A_N  = 16384;
constexpr int C_N  = 81;
constexpr int TOPK = 64;
constexpr int DNT  = 256;            // decode kernel block size
constexpr int NBINS = 232;           // score-bit bins covering (0.3, 1.0)
constexpr int CAP   = 512;           // candidate band capacity (pow2, 8/lane)
constexpr unsigned BIN_BASE = 0x3E99u;   // __float_as_uint(0.3f) >> 16

// sigmoid+transpose tile: 64 anchors x 81 classes per block.
// TA=64 (was 128): 21.8 KB LDS -> 7 blocks/CU (was 3). Phase-2 with
// al4 in [0,16): lane bank stride 20 mod 32 over 16 lanes + cc-offset
// disjointness across lane quartets -> 2-way conflicts max (free, m136).
constexpr int TA   = 64;
constexpr int TPAD = 85;
constexpr int TNT  = 256;
constexpr int TILE_ELEMS = TA * C_N;       // 5184
constexpr int TILE_F4    = (TA / 4) * C_N; // 1296 float4 stores per tile

constexpr int SNT = 256;             // fused select+nms block size

// ---------------------------------------------------------------------------
// Kernel 1: SSD box decode (unchanged — bit-exact vs ref across rounds 1-8).
// ---------------------------------------------------------------------------
__global__ __launch_bounds__(DNT) void decode_kernel(const float4* __restrict__ loc,
                                                     const float4* __restrict__ anch,
                                                     float4* __restrict__ boxes) {
    int i = blockIdx.x * DNT + threadIdx.x;
    int a = i & (A_N - 1);
    float4 l  = loc[i];
    float4 an = anch[a];
    float cx = an.x + (l.x * 0.1f) * an.z;
    float cy = an.y + (l.y * 0.1f) * an.w;
    float w  = an.z * expf(l.z * 0.2f);
    float h  = an.w * expf(l.w * 0.2f);
    float x1 = cx - w * 0.5f;
    float y1 = cy - h * 0.5f;
    boxes[i] = make_float4(x1, y1, x1 + w, y1 + h);
}

// ---------------------------------------------------------------------------
// Kernel 1b: fused sigmoid + transpose, v3 (TA=64 for occupancy; 2-way-max
// LDS conflicts in phase 2). Sigmoid expression identical to all passing
// rounds; stored fp32 values bit-identical.
// ---------------------------------------------------------------------------
__global__ __launch_bounds__(TNT) void sigT_kernel(const float* __restrict__ conf,
                                                   float* __restrict__ scoresT) {
    __shared__ float tile[TA][TPAD];

    const int a0 = blockIdx.x * TA;
    const int b  = blockIdx.y;
    const int t  = threadIdx.x;

    const float* src = conf + ((size_t)b * A_N + a0) * C_N;
#pragma unroll
    for (int i = 0; i < (TILE_ELEMS + TNT - 1) / TNT; ++i) {
        int idx = i * TNT + t;
        if (idx < TILE_ELEMS) {
            float x  = src[idx];                   // fully coalesced
            int   al = idx / C_N;
            int   cc = idx - al * C_N;
            tile[al][cc] = 1.0f / (1.0f + expf(-x));   // writes contiguous: conflict-free
        }
    }
    __syncthreads();
    float* dst = scoresT + (size_t)b * C_N * A_N + a0;
#pragma unroll
    for (int i = 0; i < (TILE_F4 + TNT - 1) / TNT; ++i) {
        int idx4 = i * TNT + t;
        if (idx4 < TILE_F4) {
            int cc  = idx4 >> 4;                   // 16 float4 per class row
            int al4 = idx4 & 15;
            float4 v;
            v.x = tile[al4 * 4 + 0][cc];
            v.y = tile[al4 * 4 + 1][cc];
            v.z = tile[al4 * 4 + 2][cc];
            v.w = tile[al4 * 4 + 3][cc];
            ((float4*)(dst + (size_t)cc * A_N))[al4] = v;   // dwordx4 stores
        }
    }
}

// ---------------------------------------------------------------------------
// Kernel 2: FUSED select + NMS — one 256-thread block per (b,c).
// Semantics verbatim from the passing rounds 4-8: same bin formula, band walk
// with refill + clamp, key = (score_bits<<32)|~idx (unique keys => sorted
// order is unique, independent of compaction arrival order), same wave
// bitonic sort, same IoU operand order, same accept/output logic.
// New decomposition only: hist+compact run on all 4 waves (high-BW streaming),
// sort+scan on wave 0 (serial tails overlap with other resident blocks),
// box gather on all 256 threads. No ghist/gcand global round-trip.
// ---------------------------------------------------------------------------
__global__ __launch_bounds__(SNT, 4) void select_nms_kernel(
        const float* __restrict__ scoresT,
        const float4* __restrict__ boxes,
        float* __restrict__ out) {
    __shared__ int hist[NBINS];
    __shared__ unsigned long long cand[CAP];
    __shared__ float4 cbox[CAP];
    __shared__ int s_cnt, s_acc, s_kout;

    const int bc   = blockIdx.x;           // b*C_N + c
    const int b    = bc / C_N;
    const int t    = threadIdx.x;
    const int lane = t & 63;
    const int wv   = t >> 6;

    for (int i = t; i < NBINS; i += SNT) hist[i] = 0;
    if (t == 0) { s_acc = 0; s_kout = 0; }
    __syncthreads();

    const float4* sptr = (const float4*)(scoresT + (size_t)bc * A_N);
    const float4* bptr = boxes + (size_t)b * A_N;
    float* optr = out + (size_t)bc * TOPK * 5;

    // --- pass 1: histogram (256 threads, coalesced float4 reads) ---
    for (int i = 0; i < A_N / 4 / SNT; ++i) {      // 16 iterations
        float4 s4 = sptr[t + SNT * i];
        float s[4] = {s4.x, s4.y, s4.z, s4.w};
#pragma unroll
        for (int q = 0; q < 4; ++q) {
            if (s[q] > 0.3f) {
                unsigned u = __float_as_uint(s[q]);
                int bin = (int)(u >> 16) - (int)BIN_BASE;
                bin = bin < 0 ? 0 : (bin > NBINS - 1 ? NBINS - 1 : bin);
                atomicAdd(&hist[bin], 1);
            }
        }
    }
    __syncthreads();

    // Accepted boxes: one per lane of wave 0, in registers.
    float rx1 = 0.f, ry1 = 0.f, rx2 = 0.f, ry2 = 0.f, rar = 0.f;
    int acc = 0, kout = 0;                 // live on wave 0; mirrored via s_acc

    int bin_hi = NBINS;
    for (;;) {
        // --- band walk (redundant on all threads; wave-uniform LDS reads) ---
        int lo = bin_hi, tot = 0;
        while (lo > 0) {
            int cnt = hist[lo - 1];
            if (tot + cnt > CAP) {
                if (tot == 0) { lo--; }            // single bin > CAP: take it (clamped)
                break;
            }
            tot += cnt; lo--;
        }
        const int bin_lo = lo;
        if (bin_lo == bin_hi) break;               // all bins consumed -> exhausted
        if (t == 0) s_cnt = 0;
        __syncthreads();

        // --- pass 2: compact this band into LDS (256 threads, L2-warm reads) ---
        for (int i = 0; i < A_N / 4 / SNT; ++i) {
            float4 s4 = sptr[t + SNT * i];
            float s[4] = {s4.x, s4.y, s4.z, s4.w};
#pragma unroll
            for (int q = 0; q < 4; ++q) {
                if (s[q] > 0.3f) {
                    unsigned u = __float_as_uint(s[q]);
                    int bin = (int)(u >> 16) - (int)BIN_BASE;
                    bin = bin < 0 ? 0 : (bin > NBINS - 1 ? NBINS - 1 : bin);
                    if (bin >= bin_lo && bin < bin_hi) {
                        int slot = atomicAdd(&s_cnt, 1);
                        if (slot < CAP) {
                            unsigned a = (unsigned)(4 * (t + SNT * i) + q);
                            cand[slot] = ((unsigned long long)u << 32) | (unsigned)(~a);
                        }
                    }
                }
            }
        }
        __syncthreads();
        int C = s_cnt; if (C > CAP) C = CAP;       // uniform across block

        if (C > 0) {
            // --- wave-0 register bitonic sort (no barriers needed in-wave) ---
            if (wv == 0) {
                unsigned long long key[8];
#pragma unroll
                for (int r = 0; r < 8; ++r) {
                    int sidx = r * 64 + lane;
                    key[r] = (sidx < C) ? cand[sidx] : 0ull;   // pad: 0 < any real key
                }
#pragma unroll
                for (int k = 2; k <= CAP; k <<= 1) {
#pragma unroll
                    for (int j = k >> 1; j > 0; j >>= 1) {
                        if (j >= 64) {
                            int jr = j >> 6;               // 1,2,4: in-lane pairs
#pragma unroll
                            for (int r = 0; r < 8; ++r) {
                                int rp = r ^ jr;
                                if (rp > r) {
                                    int e = r * 64 + lane;
                                    bool up = ((e & k) == 0);
                                    unsigned long long va = key[r], vb = key[rp];
                                    bool sw = up ? (va < vb) : (va > vb);
                                    if (sw) { key[r] = vb; key[rp] = va; }
                                }
                            }
                        } else {                            // cross-lane via shfl
#pragma unroll
                            for (int r = 0; r < 8; ++r) {
                                int e = r * 64 + lane;
                                bool up    = ((e & k) == 0);
                                bool isLow = ((lane & j) == 0);
                                unsigned long long va = key[r];
                                unsigned long long vb = __shfl_xor(va, j, 64);
                                bool keepMax = (up == isLow);
                                key[r] = keepMax ? (va > vb ? va : vb)
                                                 : (va < vb ? va : vb);
                            }
                        }
                    }
                }
#pragma unroll
                for (int r = 0; r < 8; ++r) cand[r * 64 + lane] = key[r];
            }
            __syncthreads();

            // --- gather candidate boxes into LDS (256 threads, 2 each) ---
            for (int e = t; e < CAP; e += SNT)
                if (e < C) cbox[e] = bptr[(int)(~(unsigned)cand[e])];
            __syncthreads();

            // --- ordered greedy scan on wave 0 (1-deep prefetch from LDS) ---
            if (wv == 0) {
                int ts = 0;
                unsigned long long k0 = cand[0];
                float4 cb = cbox[0];
                while (ts < C) {
                    unsigned long long nk = 0ull;
                    float4 nb = cb;
                    if (ts + 1 < C) { nk = cand[ts + 1]; nb = cbox[ts + 1]; }
                    float sc = __uint_as_float((unsigned)(k0 >> 32));
                    float ca = (cb.z - cb.x) * (cb.w - cb.y);
                    bool over = false;
                    if (lane < acc) {
                        float tlx = fmaxf(rx1, cb.x);
                        float tly = fmaxf(ry1, cb.y);
                        float brx = fminf(rx2, cb.z);
                        float bry = fminf(ry2, cb.w);
                        float iw  = fmaxf(brx - tlx, 0.0f);
                        float ih  = fmaxf(bry - tly, 0.0f);
                        float inter = iw * ih;
                        float iou = inter / (rar + ca - inter); // ref operand order
                        over = iou > 0.5f;
                    }
                    if (!__any(over)) {
                        if (lane == acc) { rx1 = cb.x; ry1 = cb.y; rx2 = cb.z; ry2 = cb.w; rar = ca; }
                        if (lane == 0) {
                            float* o = optr + (size_t)kout * 5;
                            o[0] = sc; o[1] = cb.x; o[2] = cb.y; o[3] = cb.z; o[4] = cb.w;
                        }
                        acc++; kout++;                      // wave-uniform
                        if (acc == TOPK) break;
                    }
                    ++ts; k0 = nk; cb = nb;
                }
                if (lane == 0) { s_acc = acc; s_kout = kout; }
            }
            __syncthreads();
            if (s_acc >= TOPK) break;                      // uniform
        }
        bin_hi = bin_lo;
    }

    // Zero-fill remaining rows (harness poisons d_out with 0xAA every launch).
    {
        const int ko = s_kout;                             // uniform (post-barrier)
        float* o  = optr + (size_t)ko * 5;
        int   rem = (TOPK - ko) * 5;
        for (int i = t; i < rem; i += SNT) o[i] = 0.0f;
    }
}

// ---------------------------------------------------------------------------
// Fallback: standalone one-wave NMS reading strided conf (proven r6-8 path),
// used only if d_ws is too small for scoresT.
// ---------------------------------------------------------------------------
__device__ __forceinline__ void sort_gather_scan64(
        unsigned long long* cand, float4* cbox, int C, int lane,
        const float4* __restrict__ bptr, float* __restrict__ optr,
        float& rx1, float& ry1, float& rx2, float& ry2, float& rar,
        int& acc, int& kout) {
    unsigned long long key[8];
#pragma unroll
    for (int r = 0; r < 8; ++r) {
        int sidx = r * 64 + lane;
        key[r] = (sidx < C) ? cand[sidx] : 0ull;
    }
#pragma unroll
    for (int k = 2; k <= CAP; k <<= 1) {
#pragma unroll
        for (int j = k >> 1; j > 0; j >>= 1) {
            if (j >= 64) {
                int jr = j >> 6;
#pragma unroll
                for (int r = 0; r < 8; ++r) {
                    int rp = r ^ jr;
                    if (rp > r) {
                        int e = r * 64 + lane;
                        bool up = ((e & k) == 0);
                        unsigned long long va = key[r], vb = key[rp];
                        bool sw = up ? (va < vb) : (va > vb);
                        if (sw) { key[r] = vb; key[rp] = va; }
                    }
                }
            } else {
#pragma unroll
                for (int r = 0; r < 8; ++r) {
                    int e = r * 64 + lane;
                    bool up    = ((e & k) == 0);
                    bool isLow = ((lane & j) == 0);
                    unsigned long long va = key[r];
                    unsigned long long vb = __shfl_xor(va, j, 64);
                    bool keepMax = (up == isLow);
                    key[r] = keepMax ? (va > vb ? va : vb) : (va < vb ? va : vb);
                }
            }
        }
    }
    __syncthreads();
#pragma unroll
    for (int r = 0; r < 8; ++r) cand[r * 64 + lane] = key[r];
    __syncthreads();
#pragma unroll
    for (int r = 0; r < 8; ++r) {
        int e = r * 64 + lane;
        if (e < C) cbox[e] = bptr[(int)(~(unsigned)cand[e])];
    }
    __syncthreads();

    int t = 0;
    unsigned long long k0 = cand[0];
    float4 cb = cbox[0];
    while (t < C) {
        unsigned long long nk = 0ull;
        float4 nb = cb;
        if (t + 1 < C) { nk = cand[t + 1]; nb = cbox[t + 1]; }
        float sc = __uint_as_float((unsigned)(k0 >> 32));
        float ca = (cb.z - cb.x) * (cb.w - cb.y);
        bool over = false;
        if (lane < acc) {
            float tlx = fmaxf(rx1, cb.x);
            float tly = fmaxf(ry1, cb.y);
            float brx = fminf(rx2, cb.z);
            float bry = fminf(ry2, cb.w);
            float iw  = fmaxf(brx - tlx, 0.0f);
            float ih  = fmaxf(bry - tly, 0.0f);
            float inter = iw * ih;
            float iou = inter / (rar + ca - inter);
            over = iou > 0.5f;
        }
        if (!__any(over)) {
            if (lane == acc) { rx1 = cb.x; ry1 = cb.y; rx2 = cb.z; ry2 = cb.w; rar = ca; }
            if (lane == 0) {
                float* o = optr + (size_t)kout * 5;
                o[0] = sc; o[1] = cb.x; o[2] = cb.y; o[3] = cb.z; o[4] = cb.w;
            }
            acc++; kout++;
            if (acc == TOPK) break;
        }
        ++t; k0 = nk; cb = nb;
    }
}

__global__ __launch_bounds__(64, 4) void nms_fallback(const float* __restrict__ conf,
                                                      const float4* __restrict__ boxes,
                                                      float* __restrict__ out) {
    __shared__ int hist[NBINS];
    __shared__ unsigned long long cand[CAP];
    __shared__ float4 cbox[CAP];
    __shared__ int s_cnt;

    const int c    = blockIdx.x;
    const int b    = blockIdx.y;
    const int lane = threadIdx.x;

    const float4* bptr = boxes + (size_t)b * A_N;
    const float*  cptr = conf + (size_t)b * A_N * C_N + c;
    float* optr = out + (size_t)(b * C_N + c) * TOPK * 5;

    for (int i = lane; i < NBINS; i += 64) hist[i] = 0;
    __syncthreads();
    for (int i = 0; i < A_N / 256; ++i) {
        int a0 = 4 * (lane + 64 * i);
#pragma unroll
        for (int q = 0; q < 4; ++q) {
            float x = cptr[(size_t)(a0 + q) * C_N];
            float s = 1.0f / (1.0f + expf(-x));
            if (s > 0.3f) {
                unsigned u = __float_as_uint(s);
                int bin = (int)(u >> 16) - (int)BIN_BASE;
                bin = bin < 0 ? 0 : (bin > NBINS - 1 ? NBINS - 1 : bin);
                atomicAdd(&hist[bin], 1);
            }
        }
    }
    __syncthreads();

    float rx1 = 0.f, ry1 = 0.f, rx2 = 0.f, ry2 = 0.f, rar = 0.f;
    int acc = 0, kout = 0;
    int bin_hi = NBINS;
    for (;;) {
        int lo = bin_hi, tot = 0;
        while (lo > 0) {
            int cnt = hist[lo - 1];
            if (tot + cnt > CAP) { if (tot == 0) { lo--; } break; }
            tot += cnt; lo--;
        }
        const int bin_lo = lo;
        if (bin_lo == bin_hi) break;
        if (lane == 0) s_cnt = 0;
        __syncthreads();
        for (int i = 0; i < A_N / 256; ++i) {
            int a0 = 4 * (lane + 64 * i);
#pragma unroll
            for (int q = 0; q < 4; ++q) {
                float x = cptr[(size_t)(a0 + q) * C_N];
                float s = 1.0f / (1.0f + expf(-x));
                if (s > 0.3f) {
                    unsigned u = __float_as_uint(s);
                    int bin = (int)(u >> 16) - (int)BIN_BASE;
                    bin = bin < 0 ? 0 : (bin > NBINS - 1 ? NBINS - 1 : bin);
                    if (bin >= bin_lo && bin < bin_hi) {
                        int slot = atomicAdd(&s_cnt, 1);
                        if (slot < CAP)
                            cand[slot] = ((unsigned long long)u << 32) | (unsigned)(~(unsigned)(a0 + q));
                    }
                }
            }
        }
        __syncthreads();
        int C = s_cnt; if (C > CAP) C = CAP;
        if (C > 0)
            sort_gather_scan64(cand, cbox, C, lane, bptr, optr,
                               rx1, ry1, rx2, ry2, rar, acc, kout);
        if (acc == TOPK) break;
        bin_hi = bin_lo;
    }
    {
        float* o  = optr + (size_t)kout * 5;
        int   rem = (TOPK - kout) * 5;
        for (int i = lane; i < rem; i += 64) o[i] = 0.0f;
    }
}

extern "C" void kernel_launch(void* const* d_in, const int* in_sizes, int n_in,
                              void* d_out, int out_size, void* d_ws, size_t ws_size,
                              hipStream_t stream) {
    const float* loc     = (const float*)d_in[0];   // [B, A, 4]
    const float* conf    = (const float*)d_in[1];   // [B, A, C]
    const float* anchors = (const float*)d_in[2];   // [A, 4]
    float* out = (float*)d_out;                     // [B, C, TOPK, 5]

    const size_t boxes_bytes  = (size_t)B_N * A_N * sizeof(float4);          // 4 MB
    const size_t scores_bytes = (size_t)B_N * C_N * A_N * sizeof(float);     // 85 MB

    float4* boxes = (float4*)d_ws;

    decode_kernel<<<(B_N * A_N) / DNT, DNT, 0, stream>>>(
        (const float4*)loc, (const float4*)anchors, boxes);

    if (ws_size >= boxes_bytes + scores_bytes) {
        float* scoresT = (float*)((char*)d_ws + boxes_bytes);
        sigT_kernel<<<dim3(A_N / TA, B_N), TNT, 0, stream>>>(conf, scoresT);
        select_nms_kernel<<<dim3(B_N * C_N), SNT, 0, stream>>>(scoresT, boxes, out);
    } else {
        // fallback: strided conf reads, in-wave histogram (proven semantics)
        nms_fallback<<<dim3(C_N, B_N), 64, 0, stream>>>(conf, boxes, out);
    }
}